// Round 11
// baseline (703.842 us; speedup 1.0000x reference)
//
#include <hip/hip_runtime.h>

typedef unsigned short ushort_t;
typedef unsigned int uint32;
typedef __attribute__((ext_vector_type(8))) unsigned short ushort8;
typedef __attribute__((ext_vector_type(8))) __bf16 bf16x8;
typedef __attribute__((ext_vector_type(4))) float f32x4;

__device__ __forceinline__ ushort_t f2b(float f) {
    union { float f; uint32 u; } v; v.f = f;
    uint32 r = v.u + 0x7fffu + ((v.u >> 16) & 1u);
    return (ushort_t)(r >> 16);
}
__device__ __forceinline__ float b2f(ushort_t b) {
    union { uint32 u; float f; } v; v.u = ((uint32)b) << 16;
    return v.f;
}
__device__ __forceinline__ float sigm(float x) { return 1.f / (1.f + __expf(-x)); }

__device__ __forceinline__ void gload_lds16(const void* g, void* l) {
    __builtin_amdgcn_global_load_lds(
        (__attribute__((address_space(1))) void*)g,
        (__attribute__((address_space(3))) void*)l, 16, 0, 0);
}

// epilogues
constexpr int EPI_RELU  = 1;  // bf16 relu(acc+bias) -> obf (q for s==2)
constexpr int EPI_FQ    = 2;  // merged: col<1024 feat=acc+bias+res; col>=1024 q=relu(acc+bias)
constexpr int EPI_SIG   = 3;  // rowsum sigmoid(acc) -> dsum[(by*2+wc)][z*256+row]
constexpr int EPI_XG    = 4;  // bf16 acc -> obf[z*oB + row*ldo + col]  (XGt)
constexpr int EPI_NEGCW = 5;  // bf16 -acc*cw[z*128+col] -> obf (Htn)
constexpr int EPI_Y     = 6;  // bf16 res + acc -> obf (catb slice)
constexpr int EPI_OUTT  = 7;  // fp32 acc+bias[row]; row=outchan, col=pixel -> NCHW coalesced

struct GemmP {
    const ushort_t* A; const ushort_t* B;
    const ushort_t* A2; const ushort_t* B2;     // AMODE==2 second source (gk >= 256)
    long long aBatch, bBatch, a2Batch, b2Batch;
    int lda, ldb, lda2, ldb2;
    int Ksub, kSplit, dil;
    const float* bias;
    const ushort_t* res; long long resBatch; int ldres;
    ushort_t* obf; long long oBatch; int ldo;
    ushort_t* obf2;
    float* of32;
    const float* cw;
    const float* rscale;   // AMODE==2: per-row scale of A2 (d factor)
    float* dsum;
    const ushort_t* zpage;
};

// ---------------------------------------------------------------------------
// BIG implicit-GEMM, 256x256 tile, BK=64, 8 waves (512 thr), 128KB LDS,
// 2-deep counted-vmcnt pipeline (T3/T4 "minimum 2-phase" at K-tile grain):
//   prologue: stage(0->buf0), stage(1->buf1)        [16 loads in flight]
//   iter t:   vmcnt(8)  (tile t landed; tile t+1 stays in flight ACROSS the
//             barrier — never drain to 0 mid-loop)
//             s_barrier ; compute(t) from buf[t&1] (24 ds_read_b128 + 64 MFMA
//             per wave, compiler-scheduled lgkmcnt) ; s_barrier ;
//             stage(t+2 -> buf[t&1])                 [8 loads/thread]
// Safety: every wave's vmcnt precedes the barrier => post-barrier ALL waves'
// tile-t LDS writes landed; buf overwrite only after all-read barrier.
// LDS image S[r][g] = G[r][g ^ (r&7)] via pre-swizzled per-lane source;
// reads apply the same XOR (conflict-free, r3-verified). OOB conv taps use
// an 8KB zero page. Split-K=4 (grid 64x4 = 256 blocks = 1/CU); tap geometry
// computed per K-tile (no alignment assumption). bf16 partials out.
// ---------------------------------------------------------------------------
__global__ __launch_bounds__(512, 2) void gemm_big256(GemmP p) {
    __shared__ __align__(16) ushort_t aT[2][256 * 64];
    __shared__ __align__(16) ushort_t bT[2][256 * 64];
    const int tid = threadIdx.x;
    const int z = blockIdx.z;
    const int m0 = blockIdx.x * 256;
    const int lane = tid & 63, wid = tid >> 6;      // 8 waves
    const int l15 = lane & 15, l16 = lane >> 4;
    const int wr = wid >> 2, wc = wid & 3;          // 2 x 4 wave grid
    const int lrow = lane >> 3;
    const int sgran = (lane & 7) ^ lrow;            // pre-swizzled source granule

    int ayy[4], axx[4];
    const ushort_t* aBase[4];
    const ushort_t* bBase[4];
    const long long bbOff = (long long)(m0 >> 8) * 262144;  // tile within one image
#pragma unroll
    for (int i = 0; i < 4; ++i) {
        int row = wid * 32 + i * 8 + lrow;          // 0..255
        int m = m0 + row;
        ayy[i] = (m >> 4) & 15; axx[i] = m & 15;
        aBase[i] = p.A + bbOff + sgran * 8;
        bBase[i] = p.B + (long long)row * p.ldb + sgran * 8;
    }

    f32x4 acc[8][4];
#pragma unroll
    for (int i = 0; i < 8; ++i)
#pragma unroll
        for (int j = 0; j < 4; ++j) acc[i][j] = (f32x4){0.f, 0.f, 0.f, 0.f};

    const int gk0 = z * p.kSplit;
    const int iters = p.Ksub >> 6;

    auto stage = [&](int t, int buf) {
        const int gk = gk0 + t * 64;
        const int tap = gk >> 10, kin = gk & 1023;
        int dy = 0, dx = 0;
        if (tap < 9) { int ky = tap / 3; dy = (ky - 1) * p.dil; dx = (tap - ky * 3 - 1) * p.dil; }
#pragma unroll
        for (int i = 0; i < 4; ++i) {
            int iy = ayy[i] + dy, ix = axx[i] + dx;
            bool ok = ((unsigned)iy < 16u) && ((unsigned)ix < 16u);
            const ushort_t* ga = ok ? (aBase[i] + (((iy << 4) + ix) << 10) + kin)
                                    : (p.zpage + sgran * 8);
            gload_lds16(ga, &aT[buf][(wid * 32 + i * 8) * 64]);
        }
#pragma unroll
        for (int i = 0; i < 4; ++i)
            gload_lds16(bBase[i] + gk, &bT[buf][(wid * 32 + i * 8) * 64]);
    };

    stage(0, 0);
    if (iters > 1) stage(1, 1);

    for (int t = 0; t < iters; ++t) {
        const int buf = t & 1;
        if (t + 1 < iters)
            asm volatile("s_waitcnt vmcnt(8)" ::: "memory");
        else
            asm volatile("s_waitcnt vmcnt(0)" ::: "memory");
        __builtin_amdgcn_s_barrier();
#pragma unroll
        for (int ks = 0; ks < 2; ++ks) {
            bf16x8 af[8], bfr[4];
#pragma unroll
            for (int mi = 0; mi < 8; ++mi) {
                int rr = wr * 128 + mi * 16 + l15;
                int cc = (ks * 32 + l16 * 8) ^ ((rr & 7) << 3);
                af[mi] = __builtin_bit_cast(bf16x8, *(const ushort8*)&aT[buf][rr * 64 + cc]);
            }
#pragma unroll
            for (int ni = 0; ni < 4; ++ni) {
                int rr = wc * 64 + ni * 16 + l15;
                int cc = (ks * 32 + l16 * 8) ^ ((rr & 7) << 3);
                bfr[ni] = __builtin_bit_cast(bf16x8, *(const ushort8*)&bT[buf][rr * 64 + cc]);
            }
#pragma unroll
            for (int mi = 0; mi < 8; ++mi)
#pragma unroll
                for (int ni = 0; ni < 4; ++ni)
                    acc[mi][ni] = __builtin_amdgcn_mfma_f32_16x16x32_bf16(af[mi], bfr[ni], acc[mi][ni], 0, 0, 0);
        }
        __builtin_amdgcn_s_barrier();
        if (t + 2 < iters) stage(t + 2, buf);
    }

    // epilogue: bf16 split-K partial, coalesced
#pragma unroll
    for (int mi = 0; mi < 8; ++mi)
#pragma unroll
        for (int ni = 0; ni < 4; ++ni) {
            int gcol = wc * 64 + ni * 16 + l15;
            int growb = m0 + wr * 128 + mi * 16 + l16 * 4;
#pragma unroll
            for (int r = 0; r < 4; ++r)
                p.obf[(long long)z * p.oBatch + (long long)(growb + r) * 256 + gcol] =
                    f2b(acc[mi][ni][r]);
        }
}

// Generic 4-wave MFMA GEMM: C = A.B^T, bf16 in, fp32 acc.
// AMODE==0: single source. AMODE==2: dual source (gk<256 from A/B, gk>=256
// from A2/B2 with per-row rscale on A2). AMODE==3: A's K-elements scaled by
// cw[z*128 + k] at load.
template<int BM, int BN, int AMODE, int EPI>
__global__ __launch_bounds__(256) void gemm_k(GemmP p) {
    __shared__ __align__(16) ushort_t aT[BM * 64];
    __shared__ __align__(16) ushort_t bT[BN * 64];
    constexpr int APASS = BM / 32, BPASS = BN / 32;
    constexpr int MFRAG = BM / 32, NFRAG = BN / 32;
    const int tid = threadIdx.x;
    const int z = blockIdx.z;
    const int m0 = blockIdx.x * BM, n0 = blockIdx.y * BN;
    const int lane = tid & 63, wid = tid >> 6;
    const int l15 = lane & 15, l16 = lane >> 4;
    const int wr = wid >> 1, wc = wid & 1;
    const int srow = tid >> 3, scol = (tid & 7) * 8;
    const int swcol = scol ^ ((srow & 7) << 3);

    const ushort_t* aptr[APASS];
    const ushort_t* bptr[BPASS];
    const ushort_t* aptr2[APASS];
    const ushort_t* bptr2[BPASS];
    float rsA[APASS];
#pragma unroll
    for (int pi = 0; pi < APASS; ++pi)
        aptr[pi] = p.A + (long long)z * p.aBatch +
                   (long long)(m0 + pi * 32 + srow) * p.lda + scol;
#pragma unroll
    for (int pi = 0; pi < BPASS; ++pi)
        bptr[pi] = p.B + (long long)z * p.bBatch +
                   (long long)(n0 + pi * 32 + srow) * p.ldb + scol;
    if constexpr (AMODE == 2) {
#pragma unroll
        for (int pi = 0; pi < APASS; ++pi) {
            aptr2[pi] = p.A2 + (long long)z * p.a2Batch +
                        (long long)(m0 + pi * 32 + srow) * p.lda2 + scol;
            rsA[pi] = p.rscale[z * 256 + m0 + pi * 32 + srow];
        }
#pragma unroll
        for (int pi = 0; pi < BPASS; ++pi)
            bptr2[pi] = p.B2 + (long long)z * p.b2Batch +
                        (long long)(n0 + pi * 32 + srow) * p.ldb2 + scol;
    }

    f32x4 acc[MFRAG][NFRAG];
#pragma unroll
    for (int i = 0; i < MFRAG; ++i)
#pragma unroll
        for (int j = 0; j < NFRAG; ++j) acc[i][j] = (f32x4){0.f, 0.f, 0.f, 0.f};

    ushort8 ar[APASS], br[BPASS];
    auto ldg = [&](int gk) {
        if (AMODE == 2 && gk >= 256) {
            int g2 = gk - 256;
#pragma unroll
            for (int pi = 0; pi < APASS; ++pi) {
                ushort8 t8 = *(const ushort8*)(aptr2[pi] + g2);
#pragma unroll
                for (int k = 0; k < 8; ++k) t8[k] = f2b(b2f(t8[k]) * rsA[pi]);
                ar[pi] = t8;
            }
#pragma unroll
            for (int pi = 0; pi < BPASS; ++pi) br[pi] = *(const ushort8*)(bptr2[pi] + g2);
        } else if constexpr (AMODE == 3) {
#pragma unroll
            for (int pi = 0; pi < APASS; ++pi) {
                ushort8 t8 = *(const ushort8*)(aptr[pi] + gk);
#pragma unroll
                for (int k = 0; k < 8; ++k)
                    t8[k] = f2b(b2f(t8[k]) * p.cw[(z << 7) + gk + scol + k]);
                ar[pi] = t8;
            }
#pragma unroll
            for (int pi = 0; pi < BPASS; ++pi) br[pi] = *(const ushort8*)(bptr[pi] + gk);
        } else {
#pragma unroll
            for (int pi = 0; pi < APASS; ++pi) ar[pi] = *(const ushort8*)(aptr[pi] + gk);
#pragma unroll
            for (int pi = 0; pi < BPASS; ++pi) br[pi] = *(const ushort8*)(bptr[pi] + gk);
        }
    };

    const int gk0 = z * p.kSplit;
    ldg(gk0);
    const int iters = p.Ksub >> 6;
    for (int it = 0; it < iters; ++it) {
#pragma unroll
        for (int pi = 0; pi < APASS; ++pi)
            *(ushort8*)&aT[(pi * 32 + srow) * 64 + swcol] = ar[pi];
#pragma unroll
        for (int pi = 0; pi < BPASS; ++pi)
            *(ushort8*)&bT[(pi * 32 + srow) * 64 + swcol] = br[pi];
        __syncthreads();
        if (it + 1 < iters) ldg(gk0 + (it + 1) * 64);
#pragma unroll
        for (int ks = 0; ks < 2; ++ks) {
            bf16x8 af[MFRAG], bfr[NFRAG];
#pragma unroll
            for (int mi = 0; mi < MFRAG; ++mi) {
                int rr = wr * (BM / 2) + mi * 16 + l15;
                int cc = (ks * 32 + l16 * 8) ^ ((rr & 7) << 3);
                af[mi] = __builtin_bit_cast(bf16x8, *(const ushort8*)&aT[rr * 64 + cc]);
            }
#pragma unroll
            for (int ni = 0; ni < NFRAG; ++ni) {
                int rr = wc * (BN / 2) + ni * 16 + l15;
                int cc = (ks * 32 + l16 * 8) ^ ((rr & 7) << 3);
                bfr[ni] = __builtin_bit_cast(bf16x8, *(const ushort8*)&bT[rr * 64 + cc]);
            }
#pragma unroll
            for (int mi = 0; mi < MFRAG; ++mi)
#pragma unroll
                for (int ni = 0; ni < NFRAG; ++ni)
                    acc[mi][ni] = __builtin_amdgcn_mfma_f32_16x16x32_bf16(af[mi], bfr[ni], acc[mi][ni], 0, 0, 0);
        }
        __syncthreads();
    }

    // ---------------- epilogue ----------------
#pragma unroll
    for (int mi = 0; mi < MFRAG; ++mi) {
        if constexpr (EPI == EPI_SIG) {
#pragma unroll
            for (int r = 0; r < 4; ++r) {
                float sv = 0.f;
#pragma unroll
                for (int ni = 0; ni < NFRAG; ++ni) sv += sigm(acc[mi][ni][r]);
                sv += __shfl_xor(sv, 1); sv += __shfl_xor(sv, 2);
                sv += __shfl_xor(sv, 4); sv += __shfl_xor(sv, 8);
                if (l15 == 0) {
                    int grow = m0 + wr * (BM / 2) + mi * 16 + l16 * 4 + r;
                    int q8 = blockIdx.y * 2 + wc;  // disjoint slot -> deterministic
                    p.dsum[q8 * 16384 + z * 256 + grow] = sv;
                }
            }
        } else {
#pragma unroll
            for (int ni = 0; ni < NFRAG; ++ni) {
                int gcol = n0 + wc * (BN / 2) + ni * 16 + l15;
                int growb = m0 + wr * (BM / 2) + mi * 16 + l16 * 4;
#pragma unroll
                for (int r = 0; r < 4; ++r) {
                    int grow = growb + r;
                    float v = acc[mi][ni][r];
                    if constexpr (EPI == EPI_RELU) {
                        v += p.bias[gcol]; v = fmaxf(v, 0.f);
                        p.obf[(long long)grow * p.ldo + gcol] = f2b(v);
                    } else if constexpr (EPI == EPI_FQ) {
                        v += p.bias[gcol];
                        if (gcol < 1024) {   // uniform per 64-wide tile (1024%64==0)
                            v += b2f(p.res[(long long)grow * 1024 + gcol]);
                            p.obf[(long long)grow * 1024 + gcol] = f2b(v);
                        } else {
                            v = fmaxf(v, 0.f);
                            p.obf2[(long long)grow * 128 + (gcol - 1024)] = f2b(v);
                        }
                    } else if constexpr (EPI == EPI_XG) {
                        p.obf[(long long)z * p.oBatch + (long long)grow * p.ldo + gcol] = f2b(v);
                    } else if constexpr (EPI == EPI_NEGCW) {
                        v *= -p.cw[z * 128 + gcol];
                        p.obf[(long long)z * p.oBatch + (long long)grow * p.ldo + gcol] = f2b(v);
                    } else if constexpr (EPI == EPI_Y) {
                        v = b2f(p.res[(long long)z * p.resBatch + (long long)grow * p.ldres + gcol]) + v;
                        p.obf[(long long)z * p.oBatch + (long long)grow * p.ldo + gcol] = f2b(v);
                    } else if constexpr (EPI == EPI_OUTT) {
                        v += p.bias[grow];               // row = out-channel
                        int bb = gcol >> 8, px = gcol & 255;
                        p.of32[((long long)bb * 1024 + grow) * 256 + px] = v;  // coalesced over px
                    }
                }
            }
        }
    }
}

// ---------------- small kernels ----------------

// combine 4 bf16 split-K partials + bias -> bf16 fbuf
__global__ void k_combine(const ushort_t* __restrict__ t, const float* __restrict__ fbias_s,
                          ushort_t* __restrict__ f) {
    int idx = blockIdx.x * 256 + threadIdx.x;  // x8 elements
    const long long N = 16384ll * 256;
    ushort8 a0 = *(const ushort8*)(t + (long long)idx * 8);
    ushort8 a1 = *(const ushort8*)(t + N + (long long)idx * 8);
    ushort8 a2 = *(const ushort8*)(t + 2 * N + (long long)idx * 8);
    ushort8 a3 = *(const ushort8*)(t + 3 * N + (long long)idx * 8);
    int cb = (idx * 8) & 255;
    ushort8 o;
#pragma unroll
    for (int k = 0; k < 8; ++k)
        o[k] = f2b(b2f(a0[k]) + b2f(a1[k]) + b2f(a2[k]) + b2f(a3[k]) + fbias_s[cb + k]);
    *(ushort8*)&f[(long long)idx * 8] = o;
}

// x_sum = x_cur * (1 + bilinear_up2x_align_corners(x_lat)); bf16 [B*256][1024]
__global__ void k_upsum(const float* __restrict__ xc, const float* __restrict__ xl,
                        ushort_t* __restrict__ xs) {
    __shared__ float lat[64 * 64];
    __shared__ ushort_t tile[64 * 258];
    int b = blockIdx.x, c0 = blockIdx.y * 64;
    int t = threadIdx.x;
    for (int i = t; i < 4096; i += 256)
        lat[i] = xl[((long long)(b * 1024 + c0 + (i >> 6))) * 64 + (i & 63)];
    __syncthreads();
    int y = t >> 4, x = t & 15;
    float fy = y * (7.f / 15.f); int y0 = (int)fy; float wy = fy - y0; int y1 = y0 + 1 > 7 ? 7 : y0 + 1;
    float fx = x * (7.f / 15.f); int x0 = (int)fx; float wx = fx - x0; int x1 = x0 + 1 > 7 ? 7 : x0 + 1;
    for (int cc = 0; cc < 64; ++cc) {
        float cur = xc[((long long)(b * 1024 + c0 + cc)) * 256 + t];
        const float* L = &lat[cc * 64];
        float tv = L[y0 * 8 + x0] * (1.f - wx) + L[y0 * 8 + x1] * wx;
        float bv = L[y1 * 8 + x0] * (1.f - wx) + L[y1 * 8 + x1] * wx;
        float up = tv + (bv - tv) * wy;
        tile[cc * 258 + t] = f2b(cur * (1.f + up));
    }
    __syncthreads();
    for (int i = t; i < 16384; i += 256) {
        int px = i >> 6, cc = i & 63;
        xs[((long long)(b * 256 + px)) * 1024 + c0 + cc] = tile[cc * 258 + px];
    }
}

// fused avg/max pool + channel-weight MLP; 1024 threads = 4 px-groups
__global__ void k_poolcw(const ushort_t* __restrict__ f,
                         const float* __restrict__ aw, const float* __restrict__ mw,
                         float* __restrict__ cw) {
    __shared__ float ss[4][256];
    __shared__ float mm_[4][256];
    int b = blockIdx.x, t = threadIdx.x;
    int ch = t & 255, grp = t >> 8;
    float s = 0.f, m = -3.4e38f;
    const ushort_t* base = f + (long long)b * 65536 + ch;
    for (int px = grp; px < 256; px += 4) {
        float v = b2f(base[px * 256]); s += v; m = fmaxf(m, v);
    }
    ss[grp][ch] = s; mm_[grp][ch] = m;
    __syncthreads();
    if (t < 256) {
        s = ss[0][t] + ss[1][t] + ss[2][t] + ss[3][t];
        m = fmaxf(fmaxf(mm_[0][t], mm_[1][t]), fmaxf(mm_[2][t], mm_[3][t]));
        ss[0][t] = s * (1.f / 256.f);
        mm_[0][t] = m;
    }
    __syncthreads();
    if (t < 128) {
        float s1 = 0.f, s2 = 0.f;
        const float* a = aw + t * 256; const float* w = mw + t * 256;
        for (int c = 0; c < 256; ++c) { s1 += ss[0][c] * a[c]; s2 += mm_[0][c] * w[c]; }
        s1 = fmaxf(s1, 0.f); s2 = fmaxf(s2, 0.f);
        cw[b * 128 + t] = sigm(s1 + s2);
    }
}

// d = rsqrt(sum of 8 dsum slots); write dscale (f32) + LDS-tiled transposed Pt
__global__ void k_pscale(const ushort_t* __restrict__ q, const float* __restrict__ dsum8,
                         float* __restrict__ dscale, ushort_t* __restrict__ Pt) {
    __shared__ ushort_t t[128][130];
    __shared__ float dd[128];
    int jh = blockIdx.x, b = blockIdx.y;
    int j0 = jh * 128;
    int tid = threadIdx.x;
    if (tid < 128) {
        int pix = b * 256 + j0 + tid;
        float s = 0.f;
#pragma unroll
        for (int qs = 0; qs < 8; ++qs) s += dsum8[qs * 16384 + pix];
        float r = rsqrtf(s);
        dd[tid] = r;
        dscale[pix] = r;
    }
    __syncthreads();
    int jr = tid >> 7, m = tid & 127;
    for (int i = 0; i < 64; ++i) {
        int j = i * 2 + jr;
        long long qi = ((long long)(b * 256 + j0 + j)) * 128 + m;
        t[j][m] = f2b(dd[j] * b2f(q[qi]));
    }
    __syncthreads();
    for (int i = 0; i < 64; ++i) {
        int mm = i * 2 + jr;
        Pt[((long long)b << 15) + (mm << 8) + j0 + m] = t[m][mm];
    }
}

// One-shot weight/bias packing: blocks [0,768) pack wbig for 3 stages via
// LDS; blocks >= 768 grid-stride flat regions:
//   wfq = [conv1_w(1024 rows); ck_w(128 rows)] bf16, w3b, gcnT,
//   fqbias(1152 f32 = conv1_b ++ ck_b), fbias(3x256 f32), zpage.
__global__ void k_packall(const float* r0, const float* r1, const float* r2,
                          const float* convw, const float* c1w, const float* c3w,
                          const float* ckw, const float* gcnw,
                          const float* rb0, const float* rb1, const float* rb2,
                          const float* cb, const float* c1b, const float* ckbias,
                          ushort_t* wbig3, ushort_t* wfq, ushort_t* w3b,
                          ushort_t* gcnT, float* fqbias, float* fbias,
                          ushort_t* zpage) {
    int blk = blockIdx.x, tid = threadIdx.x;
    if (blk < 768) {
        __shared__ float lw[10240];
        int s = blk >> 8, o = blk & 255;
        const float* rate = s == 0 ? r0 : (s == 1 ? r1 : r2);
        for (int i = tid; i < 9216; i += 256) lw[i] = rate[(long long)o * 9216 + i];
        for (int i = tid; i < 1024; i += 256) lw[9216 + i] = convw[(long long)o * 1024 + i];
        __syncthreads();
        ushort_t* dst = wbig3 + (long long)blk * 10240;
        for (int i = tid; i < 10240; i += 256) {
            int tap = i >> 10, ci = i & 1023;
            float v = (tap < 9) ? lw[ci * 9 + tap] : lw[9216 + ci];
            dst[i] = f2b(v);
        }
        return;
    }
    const int R1 = 262144;            // wfq: conv1_w part
    const int R2 = R1 + 32768;        // wfq: ck_w part
    const int R3 = R2 + 786432;       // w3b
    const int R4 = R3 + 65536;        // gcnT
    const int R5 = R4 + 1152;         // fqbias
    const int R6 = R5 + 768;          // fbias
    const int R7 = R6 + 4096;         // zpage
    int base = (blk - 768) * 2048 + tid * 8;
#pragma unroll
    for (int k = 0; k < 8; ++k) {
        int i = base + k;
        if (i >= R7) return;
        if (i < R1) wfq[i] = f2b(c1w[i]);
        else if (i < R2) wfq[i] = f2b(ckw[i - R1]);
        else if (i < R3) w3b[i - R2] = f2b(c3w[i - R2]);
        else if (i < R4) {
            int ii = i - R3; int c2 = ii >> 8, c1 = ii & 255;
            gcnT[ii] = f2b(gcnw[c1 * 256 + c2]);
        } else if (i < R5) {
            int ii = i - R4;
            fqbias[ii] = (ii < 1024) ? c1b[ii] : ckbias[ii - 1024];
        } else if (i < R6) {
            int ii = i - R5; int s = ii >> 8, t = ii & 255;
            const float* rb = s == 0 ? rb0 : (s == 1 ? rb1 : rb2);
            fbias[ii] = rb[t] + cb[t];
        } else {
            zpage[i - R6] = 0;
        }
    }
}

__global__ void k_sentinel(float* o, int n, float v) {
    int i = blockIdx.x * 256 + threadIdx.x; if (i < n) o[i] = v;
}

// ---------------- launch ----------------
extern "C" void kernel_launch(void* const* d_in, const int* in_sizes, int n_in,
                              void* d_out, int out_size, void* d_ws, size_t ws_size,
                              hipStream_t stream) {
    const float* x_cur  = (const float*)d_in[0];
    const float* x_lat  = (const float*)d_in[1];
    const float* conv_w = (const float*)d_in[2];
    const float* conv_b = (const float*)d_in[3];
    const float* conv1_w = (const float*)d_in[4];
    const float* conv1_b = (const float*)d_in[5];
    const float* conv3_w = (const float*)d_in[6];
    const float* conv3_b = (const float*)d_in[7];
    const float* rate_w[3] = {(const float*)d_in[8], (const float*)d_in[10], (const float*)d_in[12]};
    const float* rate_b[3] = {(const float*)d_in[9], (const float*)d_in[11], (const float*)d_in[13]};
    const float* ck_w  = (const float*)d_in[14];
    const float* ck_b  = (const float*)d_in[15];
    const float* avg_w = (const float*)d_in[16];
    const float* max_w = (const float*)d_in[17];
    const float* gcn_w = (const float*)d_in[18];
    float* out = (float*)d_out;

    char* w = (char*)d_ws;
    auto take = [&](size_t bytes) { void* p = (void*)w; w += (bytes + 255) & ~(size_t)255; return p; };
    ushort_t* xsum   = (ushort_t*)take(16384ll * 1024 * 2);    // 33.55MB
    ushort_t* feat   = (ushort_t*)take(16384ll * 1024 * 2);    // 33.55MB
    ushort_t* fbuf   = (ushort_t*)take(16384ll * 256 * 2);     // 8.39MB
    ushort_t* xgt    = (ushort_t*)take(64ll * 256 * 256 * 2);  // 8.39MB
    ushort_t* qbuf   = (ushort_t*)take(16384ll * 128 * 2);     // 4.19MB
    ushort_t* Pt     = (ushort_t*)take(64ll * 128 * 256 * 2);  // 4.19MB
    ushort_t* Htn    = (ushort_t*)take(64ll * 256 * 128 * 2);  // 4.19MB
    ushort_t* wbig3  = (ushort_t*)take(3ll * 256 * 10240 * 2); // 15.73MB
    ushort_t* wfq    = (ushort_t*)take(1152ll * 256 * 2);      // conv1_w ++ ck_w
    ushort_t* w3b    = (ushort_t*)take(1024ll * 768 * 2);
    ushort_t* gcnT   = (ushort_t*)take(256ll * 256 * 2);
    ushort_t* zpage  = (ushort_t*)take(8192);                  // 4096 ushorts, zeroed
    float*    fqbias = (float*)take(1152 * 4);
    float*    fbias  = (float*)take(3 * 256 * 4);
    float*    cwb    = (float*)take(64 * 128 * 4);
    float*    dscale = (float*)take(64 * 256 * 4);
    float*    dsum8  = (float*)take(8ll * 64 * 256 * 4);
    ushort_t* catb   = (ushort_t*)take(16384ll * 768 * 2);     // 25.17MB
    ushort_t* ftmp   = (ushort_t*)take(4ll * 16384 * 256 * 2); // 33.55MB (4 splits)
    size_t need = (size_t)(w - (char*)d_ws);                   // ~174MB

    if (need > ws_size) {
        float v = 1.0e6f + (float)(ws_size >> 20);
        k_sentinel<<<(out_size + 255) / 256, 256, 0, stream>>>(out, out_size, v);
        return;
    }

    k_packall<<<768 + 563, 256, 0, stream>>>(
        rate_w[0], rate_w[1], rate_w[2], conv_w, conv1_w, conv3_w, ck_w, gcn_w,
        rate_b[0], rate_b[1], rate_b[2], conv_b, conv1_b, ck_b,
        wbig3, wfq, w3b, gcnT, fqbias, fbias, zpage);
    k_upsum<<<dim3(64, 16), 256, 0, stream>>>(x_cur, x_lat, xsum);

    for (int s = 0; s < 3; ++s) {
        { // BIG: 256^2 tile, 2-deep counted-vmcnt pipeline, split-K=4
            GemmP p{};
            p.A = (s == 0) ? xsum : feat;
            p.B = wbig3 + (long long)s * 256 * 10240; p.ldb = 10240;
            p.Ksub = 2560; p.kSplit = 2560; p.dil = 1 << s;
            p.obf = ftmp; p.oBatch = 16384ll * 256;
            p.zpage = zpage;
            gemm_big256<<<dim3(64, 1, 4), 512, 0, stream>>>(p);
        }
        k_combine<<<2048, 256, 0, stream>>>(ftmp, fbias + s * 256, fbuf);
        k_poolcw<<<64, 1024, 0, stream>>>(fbuf, avg_w, max_w, cwb);
        if (s < 2) { // merged: feat = conv1(f)+b+xsum  AND  q = relu(f@ck^T+b)
            GemmP p{};
            p.A = fbuf; p.lda = 256; p.B = wfq; p.ldb = 256;
            p.Ksub = 256; p.bias = fqbias;
            p.res = xsum;
            p.obf = feat; p.obf2 = qbuf;
            gemm_k<64, 64, 0, EPI_FQ><<<dim3(256, 18, 1), 256, 0, stream>>>(p);
        } else {     // q only
            GemmP p{};
            p.A = fbuf; p.lda = 256; p.B = wfq + 1024 * 256; p.ldb = 256;
            p.Ksub = 256;
            p.bias = ck_b; p.obf = qbuf; p.ldo = 128;
            gemm_k<64, 64, 0, EPI_RELU><<<dim3(256, 2, 1), 256, 0, stream>>>(p);
        }
        { // dsum8 partial row-sums of sigmoid((q*cw)_i . q_j); cw folded into A-load
            GemmP p{};
            p.A = qbuf; p.aBatch = 32768; p.lda = 128;
            p.B = qbuf; p.bBatch = 32768; p.ldb = 128;
            p.Ksub = 128; p.dsum = dsum8; p.cw = cwb;
            gemm_k<64, 64, 3, EPI_SIG><<<dim3(4, 4, 64), 256, 0, stream>>>(p);
        }
        k_pscale<<<dim3(2, 64), 256, 0, stream>>>(qbuf, dsum8, dscale, Pt);
        { // XGt[b][c][j] = sum_c' gcnT[c][c'] fbuf_b[j][c']
            GemmP p{};
            p.A = gcnT; p.aBatch = 0;     p.lda = 256;
            p.B = fbuf; p.bBatch = 65536; p.ldb = 256;
            p.Ksub = 256;
            p.obf = xgt; p.oBatch = 65536; p.ldo = 256;
            gemm_k<64, 64, 0, EPI_XG><<<dim3(4, 4, 64), 256, 0, stream>>>(p);
        }
        { // Htn[b][c][m] = -cw[m] * sum_j XGt[c][j] Pt[m][j]
            GemmP p{};
            p.A = xgt; p.aBatch = 65536; p.lda = 256;
            p.B = Pt;  p.bBatch = 32768; p.ldb = 256;
            p.Ksub = 256; p.cw = cwb;
            p.obf = Htn; p.oBatch = 32768; p.ldo = 128;
            gemm_k<64, 64, 0, EPI_NEGCW><<<dim3(4, 2, 64), 256, 0, stream>>>(p);
        }
        { // Y = X + X@G - (d*q)@H : K=384 dual-source -> catb slice
            GemmP p{};
            p.A = fbuf; p.aBatch = 65536; p.lda = 256;
            p.B = gcnT; p.bBatch = 0;     p.ldb = 256;
            p.A2 = qbuf; p.a2Batch = 32768; p.lda2 = 128; p.rscale = dscale;
            p.B2 = Htn;  p.b2Batch = 32768; p.ldb2 = 128;
            p.Ksub = 384;
            p.res = fbuf; p.resBatch = 65536; p.ldres = 256;
            p.obf = catb + s * 256; p.oBatch = 256ll * 768; p.ldo = 768;
            gemm_k<64, 64, 2, EPI_Y><<<dim3(4, 4, 64), 256, 0, stream>>>(p);
        }
    }
    { // out[bb][o][px] = sum_k w3[o][k] cat[px][k] + conv3_b[o]
        GemmP p{};
        p.A = w3b;  p.lda = 768;
        p.B = catb; p.ldb = 768;
        p.Ksub = 768; p.bias = conv3_b; p.of32 = out;
        gemm_k<64, 128, 0, EPI_OUTT><<<dim3(16, 128, 1), 256, 0, stream>>>(p);
    }
}

// Round 12
// 691.338 us; speedup vs baseline: 1.0181x; 1.0181x over previous
//
#include <hip/hip_runtime.h>

typedef unsigned short ushort_t;
typedef unsigned int uint32;
typedef __attribute__((ext_vector_type(8))) unsigned short ushort8;
typedef __attribute__((ext_vector_type(8))) __bf16 bf16x8;
typedef __attribute__((ext_vector_type(4))) float f32x4;

__device__ __forceinline__ ushort_t f2b(float f) {
    union { float f; uint32 u; } v; v.f = f;
    uint32 r = v.u + 0x7fffu + ((v.u >> 16) & 1u);
    return (ushort_t)(r >> 16);
}
__device__ __forceinline__ float b2f(ushort_t b) {
    union { uint32 u; float f; } v; v.u = ((uint32)b) << 16;
    return v.f;
}
__device__ __forceinline__ float sigm(float x) { return 1.f / (1.f + __expf(-x)); }

__device__ __forceinline__ void gload_lds16(const void* g, void* l) {
    __builtin_amdgcn_global_load_lds(
        (__attribute__((address_space(1))) void*)g,
        (__attribute__((address_space(3))) void*)l, 16, 0, 0);
}

// epilogues
constexpr int EPI_RELU  = 1;  // bf16 relu(acc+bias) -> obf (q for s==2)
constexpr int EPI_FQ    = 2;  // merged: col<1024 feat=acc+bias+res; col>=1024 q=relu(acc+bias)
constexpr int EPI_SIG   = 3;  // rowsum sigmoid(acc) -> dsum[(by*2+wc)][z*256+row]
constexpr int EPI_XG    = 4;  // bf16 acc -> obf[z*oB + row*ldo + col]  (XGt)
constexpr int EPI_NEGCW = 5;  // bf16 -acc*cw[z*128+col] -> obf (Htn)
constexpr int EPI_Y     = 6;  // bf16 res + acc -> obf (catb slice)
constexpr int EPI_OUTT  = 7;  // fp32 acc+bias[row]; row=outchan, col=pixel -> NCHW coalesced

struct GemmP {
    const ushort_t* A; const ushort_t* B;
    const ushort_t* A2; const ushort_t* B2;     // AMODE==2 second source (gk >= 256)
    long long aBatch, bBatch, a2Batch, b2Batch;
    int lda, ldb, lda2, ldb2;
    int Ksub, kSplit, dil;
    const float* bias;
    const ushort_t* res; long long resBatch; int ldres;
    ushort_t* obf; long long oBatch; int ldo;
    ushort_t* obf2;
    float* of32;
    const float* cw;
    const float* rscale;   // AMODE==2: per-row scale of A2 (d factor)
    float* dsum;
    const ushort_t* zpage;
};

// ---------------------------------------------------------------------------
// BIG implicit-GEMM (9 dilated conv taps + conv1x1 identity tap), m97-style
// global_load_lds staging, split-K=5 (grid 1280 = 5 blocks/CU = LDS cap),
// 128x128 tile, BK=64. LDS image S[r][g] = G[r][g ^ (r&7)] via pre-swizzled
// per-lane global source; read side applies the same XOR (conflict-free,
// r3-verified: 4.7e7 -> 0). Split-K chunks are tap-aligned (2048 = 2 taps):
// tap geometry + im2col pointers hoist to a per-tap outer loop; inner 16
// K-steps only add kin. OOB rows use an 8KB zero page. bf16 partials.
// NOTE (r11 lesson): the 256^2 2-deep counted-vmcnt variant REGRESSED
// (97-102us vs this structure's 86-96us) — coarse K-tile-grain counted
// vmcnt without the fine 8-phase interleave loses the 5-blocks/CU
// cross-block overlap (m196/m230 regime gate). Keep this version.
// ---------------------------------------------------------------------------
__global__ __launch_bounds__(256) void gemm_big(GemmP p) {
    __shared__ __align__(16) ushort_t aT[128 * 64];
    __shared__ __align__(16) ushort_t bT[128 * 64];
    const int tid = threadIdx.x;
    const int z = blockIdx.z;
    const int m0 = blockIdx.x * 128, n0 = blockIdx.y * 128;
    const int lane = tid & 63, wid = tid >> 6;
    const int l15 = lane & 15, l16 = lane >> 4;
    const int wr = wid >> 1, wc = wid & 1;
    const int lrow = lane >> 3;
    const int sgran = (lane & 7) ^ lrow;

    int ayy[4], axx[4];
    const ushort_t* aBase[4];
    const ushort_t* bBase[4];
#pragma unroll
    for (int i = 0; i < 4; ++i) {
        int row = wid * 32 + i * 8 + lrow;
        int m = m0 + row;
        int bb = m >> 8;
        ayy[i] = (m >> 4) & 15; axx[i] = m & 15;
        aBase[i] = p.A + (long long)bb * 262144 + sgran * 8;
        bBase[i] = p.B + (long long)(n0 + row) * p.ldb + sgran * 8;
    }

    f32x4 acc[4][4];
#pragma unroll
    for (int i = 0; i < 4; ++i)
#pragma unroll
        for (int j = 0; j < 4; ++j) acc[i][j] = (f32x4){0.f, 0.f, 0.f, 0.f};

    const int gk0 = z * p.kSplit;          // tap-aligned
    const int ntap = p.Ksub >> 10;
    for (int ti = 0; ti < ntap; ++ti) {
        const int tap = (gk0 >> 10) + ti;
        int dy = 0, dx = 0;
        if (tap < 9) { int ky = tap / 3; dy = (ky - 1) * p.dil; dx = (tap - ky * 3 - 1) * p.dil; }
        const ushort_t* gaA[4];
        const ushort_t* gaB[4];
#pragma unroll
        for (int i = 0; i < 4; ++i) {
            int iy = ayy[i] + dy, ix = axx[i] + dx;
            bool ok = ((unsigned)iy < 16u) && ((unsigned)ix < 16u);
            gaA[i] = ok ? (aBase[i] + (((iy << 4) + ix) << 10)) : (p.zpage + sgran * 8);
            gaB[i] = bBase[i] + (tap << 10);
        }
        for (int kk = 0; kk < 16; ++kk) {
            const int kin = kk << 6;
#pragma unroll
            for (int i = 0; i < 4; ++i)
                gload_lds16(gaA[i] + kin, &aT[(wid * 32 + i * 8) * 64]);
#pragma unroll
            for (int i = 0; i < 4; ++i)
                gload_lds16(gaB[i] + kin, &bT[(wid * 32 + i * 8) * 64]);
            asm volatile("s_waitcnt vmcnt(0)" ::: "memory");
            __syncthreads();
#pragma unroll
            for (int ks = 0; ks < 2; ++ks) {
                bf16x8 af[4], bfr[4];
#pragma unroll
                for (int mi = 0; mi < 4; ++mi) {
                    int rr = wr * 64 + mi * 16 + l15;
                    int cc = (ks * 32 + l16 * 8) ^ ((rr & 7) << 3);
                    af[mi] = __builtin_bit_cast(bf16x8, *(const ushort8*)&aT[rr * 64 + cc]);
                }
#pragma unroll
                for (int ni = 0; ni < 4; ++ni) {
                    int rr = wc * 64 + ni * 16 + l15;
                    int cc = (ks * 32 + l16 * 8) ^ ((rr & 7) << 3);
                    bfr[ni] = __builtin_bit_cast(bf16x8, *(const ushort8*)&bT[rr * 64 + cc]);
                }
#pragma unroll
                for (int mi = 0; mi < 4; ++mi)
#pragma unroll
                    for (int ni = 0; ni < 4; ++ni)
                        acc[mi][ni] = __builtin_amdgcn_mfma_f32_16x16x32_bf16(af[mi], bfr[ni], acc[mi][ni], 0, 0, 0);
            }
            __syncthreads();
        }
    }
#pragma unroll
    for (int mi = 0; mi < 4; ++mi)
#pragma unroll
        for (int ni = 0; ni < 4; ++ni) {
            int gcol = n0 + wc * 64 + ni * 16 + l15;
            int growb = m0 + wr * 64 + mi * 16 + l16 * 4;
#pragma unroll
            for (int r = 0; r < 4; ++r)
                p.obf[(long long)z * p.oBatch + (long long)(growb + r) * 256 + gcol] =
                    f2b(acc[mi][ni][r]);
        }
}

// Generic 4-wave MFMA GEMM: C = A.B^T, bf16 in, fp32 acc.
// AMODE==0: single source. AMODE==2: dual source (gk<256 from A/B, gk>=256
// from A2/B2 with per-row rscale on A2). AMODE==3: A's K-elements scaled by
// cw[z*128 + k] at load.
template<int BM, int BN, int AMODE, int EPI>
__global__ __launch_bounds__(256) void gemm_k(GemmP p) {
    __shared__ __align__(16) ushort_t aT[BM * 64];
    __shared__ __align__(16) ushort_t bT[BN * 64];
    constexpr int APASS = BM / 32, BPASS = BN / 32;
    constexpr int MFRAG = BM / 32, NFRAG = BN / 32;
    const int tid = threadIdx.x;
    const int z = blockIdx.z;
    const int m0 = blockIdx.x * BM, n0 = blockIdx.y * BN;
    const int lane = tid & 63, wid = tid >> 6;
    const int l15 = lane & 15, l16 = lane >> 4;
    const int wr = wid >> 1, wc = wid & 1;
    const int srow = tid >> 3, scol = (tid & 7) * 8;
    const int swcol = scol ^ ((srow & 7) << 3);

    const ushort_t* aptr[APASS];
    const ushort_t* bptr[BPASS];
    const ushort_t* aptr2[APASS];
    const ushort_t* bptr2[BPASS];
    float rsA[APASS];
#pragma unroll
    for (int pi = 0; pi < APASS; ++pi)
        aptr[pi] = p.A + (long long)z * p.aBatch +
                   (long long)(m0 + pi * 32 + srow) * p.lda + scol;
#pragma unroll
    for (int pi = 0; pi < BPASS; ++pi)
        bptr[pi] = p.B + (long long)z * p.bBatch +
                   (long long)(n0 + pi * 32 + srow) * p.ldb + scol;
    if constexpr (AMODE == 2) {
#pragma unroll
        for (int pi = 0; pi < APASS; ++pi) {
            aptr2[pi] = p.A2 + (long long)z * p.a2Batch +
                        (long long)(m0 + pi * 32 + srow) * p.lda2 + scol;
            rsA[pi] = p.rscale[z * 256 + m0 + pi * 32 + srow];
        }
#pragma unroll
        for (int pi = 0; pi < BPASS; ++pi)
            bptr2[pi] = p.B2 + (long long)z * p.b2Batch +
                        (long long)(n0 + pi * 32 + srow) * p.ldb2 + scol;
    }

    f32x4 acc[MFRAG][NFRAG];
#pragma unroll
    for (int i = 0; i < MFRAG; ++i)
#pragma unroll
        for (int j = 0; j < NFRAG; ++j) acc[i][j] = (f32x4){0.f, 0.f, 0.f, 0.f};

    ushort8 ar[APASS], br[BPASS];
    auto ldg = [&](int gk) {
        if (AMODE == 2 && gk >= 256) {
            int g2 = gk - 256;
#pragma unroll
            for (int pi = 0; pi < APASS; ++pi) {
                ushort8 t8 = *(const ushort8*)(aptr2[pi] + g2);
#pragma unroll
                for (int k = 0; k < 8; ++k) t8[k] = f2b(b2f(t8[k]) * rsA[pi]);
                ar[pi] = t8;
            }
#pragma unroll
            for (int pi = 0; pi < BPASS; ++pi) br[pi] = *(const ushort8*)(bptr2[pi] + g2);
        } else if constexpr (AMODE == 3) {
#pragma unroll
            for (int pi = 0; pi < APASS; ++pi) {
                ushort8 t8 = *(const ushort8*)(aptr[pi] + gk);
#pragma unroll
                for (int k = 0; k < 8; ++k)
                    t8[k] = f2b(b2f(t8[k]) * p.cw[(z << 7) + gk + scol + k]);
                ar[pi] = t8;
            }
#pragma unroll
            for (int pi = 0; pi < BPASS; ++pi) br[pi] = *(const ushort8*)(bptr[pi] + gk);
        } else {
#pragma unroll
            for (int pi = 0; pi < APASS; ++pi) ar[pi] = *(const ushort8*)(aptr[pi] + gk);
#pragma unroll
            for (int pi = 0; pi < BPASS; ++pi) br[pi] = *(const ushort8*)(bptr[pi] + gk);
        }
    };

    const int gk0 = z * p.kSplit;
    ldg(gk0);
    const int iters = p.Ksub >> 6;
    for (int it = 0; it < iters; ++it) {
#pragma unroll
        for (int pi = 0; pi < APASS; ++pi)
            *(ushort8*)&aT[(pi * 32 + srow) * 64 + swcol] = ar[pi];
#pragma unroll
        for (int pi = 0; pi < BPASS; ++pi)
            *(ushort8*)&bT[(pi * 32 + srow) * 64 + swcol] = br[pi];
        __syncthreads();
        if (it + 1 < iters) ldg(gk0 + (it + 1) * 64);
#pragma unroll
        for (int ks = 0; ks < 2; ++ks) {
            bf16x8 af[MFRAG], bfr[NFRAG];
#pragma unroll
            for (int mi = 0; mi < MFRAG; ++mi) {
                int rr = wr * (BM / 2) + mi * 16 + l15;
                int cc = (ks * 32 + l16 * 8) ^ ((rr & 7) << 3);
                af[mi] = __builtin_bit_cast(bf16x8, *(const ushort8*)&aT[rr * 64 + cc]);
            }
#pragma unroll
            for (int ni = 0; ni < NFRAG; ++ni) {
                int rr = wc * (BN / 2) + ni * 16 + l15;
                int cc = (ks * 32 + l16 * 8) ^ ((rr & 7) << 3);
                bfr[ni] = __builtin_bit_cast(bf16x8, *(const ushort8*)&bT[rr * 64 + cc]);
            }
#pragma unroll
            for (int mi = 0; mi < MFRAG; ++mi)
#pragma unroll
                for (int ni = 0; ni < NFRAG; ++ni)
                    acc[mi][ni] = __builtin_amdgcn_mfma_f32_16x16x32_bf16(af[mi], bfr[ni], acc[mi][ni], 0, 0, 0);
        }
        __syncthreads();
    }

    // ---------------- epilogue ----------------
#pragma unroll
    for (int mi = 0; mi < MFRAG; ++mi) {
        if constexpr (EPI == EPI_SIG) {
#pragma unroll
            for (int r = 0; r < 4; ++r) {
                float sv = 0.f;
#pragma unroll
                for (int ni = 0; ni < NFRAG; ++ni) sv += sigm(acc[mi][ni][r]);
                sv += __shfl_xor(sv, 1); sv += __shfl_xor(sv, 2);
                sv += __shfl_xor(sv, 4); sv += __shfl_xor(sv, 8);
                if (l15 == 0) {
                    int grow = m0 + wr * (BM / 2) + mi * 16 + l16 * 4 + r;
                    int q8 = blockIdx.y * 2 + wc;  // disjoint slot -> deterministic
                    p.dsum[q8 * 16384 + z * 256 + grow] = sv;
                }
            }
        } else {
#pragma unroll
            for (int ni = 0; ni < NFRAG; ++ni) {
                int gcol = n0 + wc * (BN / 2) + ni * 16 + l15;
                int growb = m0 + wr * (BM / 2) + mi * 16 + l16 * 4;
#pragma unroll
                for (int r = 0; r < 4; ++r) {
                    int grow = growb + r;
                    float v = acc[mi][ni][r];
                    if constexpr (EPI == EPI_RELU) {
                        v += p.bias[gcol]; v = fmaxf(v, 0.f);
                        p.obf[(long long)grow * p.ldo + gcol] = f2b(v);
                    } else if constexpr (EPI == EPI_FQ) {
                        v += p.bias[gcol];
                        if (gcol < 1024) {   // uniform per 64-wide tile (1024%64==0)
                            v += b2f(p.res[(long long)grow * 1024 + gcol]);
                            p.obf[(long long)grow * 1024 + gcol] = f2b(v);
                        } else {
                            v = fmaxf(v, 0.f);
                            p.obf2[(long long)grow * 128 + (gcol - 1024)] = f2b(v);
                        }
                    } else if constexpr (EPI == EPI_XG) {
                        p.obf[(long long)z * p.oBatch + (long long)grow * p.ldo + gcol] = f2b(v);
                    } else if constexpr (EPI == EPI_NEGCW) {
                        v *= -p.cw[z * 128 + gcol];
                        p.obf[(long long)z * p.oBatch + (long long)grow * p.ldo + gcol] = f2b(v);
                    } else if constexpr (EPI == EPI_Y) {
                        v = b2f(p.res[(long long)z * p.resBatch + (long long)grow * p.ldres + gcol]) + v;
                        p.obf[(long long)z * p.oBatch + (long long)grow * p.ldo + gcol] = f2b(v);
                    } else if constexpr (EPI == EPI_OUTT) {
                        v += p.bias[grow];               // row = out-channel
                        int bb = gcol >> 8, px = gcol & 255;
                        p.of32[((long long)bb * 1024 + grow) * 256 + px] = v;  // coalesced over px
                    }
                }
            }
        }
    }
}

// ---------------- small kernels ----------------

// combine 5 bf16 split-K partials + bias -> bf16 fbuf
__global__ void k_combine(const ushort_t* __restrict__ t, const float* __restrict__ fbias_s,
                          ushort_t* __restrict__ f) {
    int idx = blockIdx.x * 256 + threadIdx.x;  // x8 elements
    const long long N = 16384ll * 256;
    ushort8 a0 = *(const ushort8*)(t + (long long)idx * 8);
    ushort8 a1 = *(const ushort8*)(t + N + (long long)idx * 8);
    ushort8 a2 = *(const ushort8*)(t + 2 * N + (long long)idx * 8);
    ushort8 a3 = *(const ushort8*)(t + 3 * N + (long long)idx * 8);
    ushort8 a4 = *(const ushort8*)(t + 4 * N + (long long)idx * 8);
    int cb = (idx * 8) & 255;
    ushort8 o;
#pragma unroll
    for (int k = 0; k < 8; ++k)
        o[k] = f2b(b2f(a0[k]) + b2f(a1[k]) + b2f(a2[k]) + b2f(a3[k]) + b2f(a4[k]) + fbias_s[cb + k]);
    *(ushort8*)&f[(long long)idx * 8] = o;
}

// x_sum = x_cur * (1 + bilinear_up2x_align_corners(x_lat)); bf16 [B*256][1024]
__global__ void k_upsum(const float* __restrict__ xc, const float* __restrict__ xl,
                        ushort_t* __restrict__ xs) {
    __shared__ float lat[64 * 64];
    __shared__ ushort_t tile[64 * 258];
    int b = blockIdx.x, c0 = blockIdx.y * 64;
    int t = threadIdx.x;
    for (int i = t; i < 4096; i += 256)
        lat[i] = xl[((long long)(b * 1024 + c0 + (i >> 6))) * 64 + (i & 63)];
    __syncthreads();
    int y = t >> 4, x = t & 15;
    float fy = y * (7.f / 15.f); int y0 = (int)fy; float wy = fy - y0; int y1 = y0 + 1 > 7 ? 7 : y0 + 1;
    float fx = x * (7.f / 15.f); int x0 = (int)fx; float wx = fx - x0; int x1 = x0 + 1 > 7 ? 7 : x0 + 1;
    for (int cc = 0; cc < 64; ++cc) {
        float cur = xc[((long long)(b * 1024 + c0 + cc)) * 256 + t];
        const float* L = &lat[cc * 64];
        float tv = L[y0 * 8 + x0] * (1.f - wx) + L[y0 * 8 + x1] * wx;
        float bv = L[y1 * 8 + x0] * (1.f - wx) + L[y1 * 8 + x1] * wx;
        float up = tv + (bv - tv) * wy;
        tile[cc * 258 + t] = f2b(cur * (1.f + up));
    }
    __syncthreads();
    for (int i = t; i < 16384; i += 256) {
        int px = i >> 6, cc = i & 63;
        xs[((long long)(b * 256 + px)) * 1024 + c0 + cc] = tile[cc * 258 + px];
    }
}

// fused avg/max pool + channel-weight MLP; 1024 threads = 4 px-groups
__global__ void k_poolcw(const ushort_t* __restrict__ f,
                         const float* __restrict__ aw, const float* __restrict__ mw,
                         float* __restrict__ cw) {
    __shared__ float ss[4][256];
    __shared__ float mm_[4][256];
    int b = blockIdx.x, t = threadIdx.x;
    int ch = t & 255, grp = t >> 8;
    float s = 0.f, m = -3.4e38f;
    const ushort_t* base = f + (long long)b * 65536 + ch;
    for (int px = grp; px < 256; px += 4) {
        float v = b2f(base[px * 256]); s += v; m = fmaxf(m, v);
    }
    ss[grp][ch] = s; mm_[grp][ch] = m;
    __syncthreads();
    if (t < 256) {
        s = ss[0][t] + ss[1][t] + ss[2][t] + ss[3][t];
        m = fmaxf(fmaxf(mm_[0][t], mm_[1][t]), fmaxf(mm_[2][t], mm_[3][t]));
        ss[0][t] = s * (1.f / 256.f);
        mm_[0][t] = m;
    }
    __syncthreads();
    if (t < 128) {
        float s1 = 0.f, s2 = 0.f;
        const float* a = aw + t * 256; const float* w = mw + t * 256;
        for (int c = 0; c < 256; ++c) { s1 += ss[0][c] * a[c]; s2 += mm_[0][c] * w[c]; }
        s1 = fmaxf(s1, 0.f); s2 = fmaxf(s2, 0.f);
        cw[b * 128 + t] = sigm(s1 + s2);
    }
}

// d = rsqrt(sum of 8 dsum slots); write dscale (f32) + LDS-tiled transposed Pt
__global__ void k_pscale(const ushort_t* __restrict__ q, const float* __restrict__ dsum8,
                         float* __restrict__ dscale, ushort_t* __restrict__ Pt) {
    __shared__ ushort_t t[128][130];
    __shared__ float dd[128];
    int jh = blockIdx.x, b = blockIdx.y;
    int j0 = jh * 128;
    int tid = threadIdx.x;
    if (tid < 128) {
        int pix = b * 256 + j0 + tid;
        float s = 0.f;
#pragma unroll
        for (int qs = 0; qs < 8; ++qs) s += dsum8[qs * 16384 + pix];
        float r = rsqrtf(s);
        dd[tid] = r;
        dscale[pix] = r;
    }
    __syncthreads();
    int jr = tid >> 7, m = tid & 127;
    for (int i = 0; i < 64; ++i) {
        int j = i * 2 + jr;
        long long qi = ((long long)(b * 256 + j0 + j)) * 128 + m;
        t[j][m] = f2b(dd[j] * b2f(q[qi]));
    }
    __syncthreads();
    for (int i = 0; i < 64; ++i) {
        int mm = i * 2 + jr;
        Pt[((long long)b << 15) + (mm << 8) + j0 + m] = t[m][mm];
    }
}

// One-shot weight/bias packing: blocks [0,768) pack wbig for 3 stages via
// LDS; blocks >= 768 grid-stride flat regions:
//   wfq = [conv1_w(1024 rows); ck_w(128 rows)] bf16, w3b, gcnT,
//   fqbias(1152 f32 = conv1_b ++ ck_b), fbias(3x256 f32), zpage.
__global__ void k_packall(const float* r0, const float* r1, const float* r2,
                          const float* convw, const float* c1w, const float* c3w,
                          const float* ckw, const float* gcnw,
                          const float* rb0, const float* rb1, const float* rb2,
                          const float* cb, const float* c1b, const float* ckbias,
                          ushort_t* wbig3, ushort_t* wfq, ushort_t* w3b,
                          ushort_t* gcnT, float* fqbias, float* fbias,
                          ushort_t* zpage) {
    int blk = blockIdx.x, tid = threadIdx.x;
    if (blk < 768) {
        __shared__ float lw[10240];
        int s = blk >> 8, o = blk & 255;
        const float* rate = s == 0 ? r0 : (s == 1 ? r1 : r2);
        for (int i = tid; i < 9216; i += 256) lw[i] = rate[(long long)o * 9216 + i];
        for (int i = tid; i < 1024; i += 256) lw[9216 + i] = convw[(long long)o * 1024 + i];
        __syncthreads();
        ushort_t* dst = wbig3 + (long long)blk * 10240;
        for (int i = tid; i < 10240; i += 256) {
            int tap = i >> 10, ci = i & 1023;
            float v = (tap < 9) ? lw[ci * 9 + tap] : lw[9216 + ci];
            dst[i] = f2b(v);
        }
        return;
    }
    const int R1 = 262144;            // wfq: conv1_w part
    const int R2 = R1 + 32768;        // wfq: ck_w part
    const int R3 = R2 + 786432;       // w3b
    const int R4 = R3 + 65536;        // gcnT
    const int R5 = R4 + 1152;         // fqbias
    const int R6 = R5 + 768;          // fbias
    const int R7 = R6 + 4096;         // zpage
    int base = (blk - 768) * 2048 + tid * 8;
#pragma unroll
    for (int k = 0; k < 8; ++k) {
        int i = base + k;
        if (i >= R7) return;
        if (i < R1) wfq[i] = f2b(c1w[i]);
        else if (i < R2) wfq[i] = f2b(ckw[i - R1]);
        else if (i < R3) w3b[i - R2] = f2b(c3w[i - R2]);
        else if (i < R4) {
            int ii = i - R3; int c2 = ii >> 8, c1 = ii & 255;
            gcnT[ii] = f2b(gcnw[c1 * 256 + c2]);
        } else if (i < R5) {
            int ii = i - R4;
            fqbias[ii] = (ii < 1024) ? c1b[ii] : ckbias[ii - 1024];
        } else if (i < R6) {
            int ii = i - R5; int s = ii >> 8, t = ii & 255;
            const float* rb = s == 0 ? rb0 : (s == 1 ? rb1 : rb2);
            fbias[ii] = rb[t] + cb[t];
        } else {
            zpage[i - R6] = 0;
        }
    }
}

__global__ void k_sentinel(float* o, int n, float v) {
    int i = blockIdx.x * 256 + threadIdx.x; if (i < n) o[i] = v;
}

// ---------------- launch ----------------
extern "C" void kernel_launch(void* const* d_in, const int* in_sizes, int n_in,
                              void* d_out, int out_size, void* d_ws, size_t ws_size,
                              hipStream_t stream) {
    const float* x_cur  = (const float*)d_in[0];
    const float* x_lat  = (const float*)d_in[1];
    const float* conv_w = (const float*)d_in[2];
    const float* conv_b = (const float*)d_in[3];
    const float* conv1_w = (const float*)d_in[4];
    const float* conv1_b = (const float*)d_in[5];
    const float* conv3_w = (const float*)d_in[6];
    const float* conv3_b = (const float*)d_in[7];
    const float* rate_w[3] = {(const float*)d_in[8], (const float*)d_in[10], (const float*)d_in[12]};
    const float* rate_b[3] = {(const float*)d_in[9], (const float*)d_in[11], (const float*)d_in[13]};
    const float* ck_w  = (const float*)d_in[14];
    const float* ck_b  = (const float*)d_in[15];
    const float* avg_w = (const float*)d_in[16];
    const float* max_w = (const float*)d_in[17];
    const float* gcn_w = (const float*)d_in[18];
    float* out = (float*)d_out;

    char* w = (char*)d_ws;
    auto take = [&](size_t bytes) { void* p = (void*)w; w += (bytes + 255) & ~(size_t)255; return p; };
    ushort_t* xsum   = (ushort_t*)take(16384ll * 1024 * 2);    // 33.55MB
    ushort_t* feat   = (ushort_t*)take(16384ll * 1024 * 2);    // 33.55MB
    ushort_t* fbuf   = (ushort_t*)take(16384ll * 256 * 2);     // 8.39MB
    ushort_t* xgt    = (ushort_t*)take(64ll * 256 * 256 * 2);  // 8.39MB
    ushort_t* qbuf   = (ushort_t*)take(16384ll * 128 * 2);     // 4.19MB
    ushort_t* Pt     = (ushort_t*)take(64ll * 128 * 256 * 2);  // 4.19MB
    ushort_t* Htn    = (ushort_t*)take(64ll * 256 * 128 * 2);  // 4.19MB
    ushort_t* wbig3  = (ushort_t*)take(3ll * 256 * 10240 * 2); // 15.73MB
    ushort_t* wfq    = (ushort_t*)take(1152ll * 256 * 2);      // conv1_w ++ ck_w
    ushort_t* w3b    = (ushort_t*)take(1024ll * 768 * 2);
    ushort_t* gcnT   = (ushort_t*)take(256ll * 256 * 2);
    ushort_t* zpage  = (ushort_t*)take(8192);                  // 4096 ushorts, zeroed
    float*    fqbias = (float*)take(1152 * 4);
    float*    fbias  = (float*)take(3 * 256 * 4);
    float*    cwb    = (float*)take(64 * 128 * 4);
    float*    dscale = (float*)take(64 * 256 * 4);
    float*    dsum8  = (float*)take(8ll * 64 * 256 * 4);
    ushort_t* catb   = (ushort_t*)take(16384ll * 768 * 2);     // 25.17MB
    ushort_t* ftmp   = (ushort_t*)take(5ll * 16384 * 256 * 2); // 41.94MB (5 splits)
    size_t need = (size_t)(w - (char*)d_ws);                   // ~182MB

    if (need > ws_size) {
        float v = 1.0e6f + (float)(ws_size >> 20);
        k_sentinel<<<(out_size + 255) / 256, 256, 0, stream>>>(out, out_size, v);
        return;
    }

    k_packall<<<768 + 563, 256, 0, stream>>>(
        rate_w[0], rate_w[1], rate_w[2], conv_w, conv1_w, conv3_w, ck_w, gcn_w,
        rate_b[0], rate_b[1], rate_b[2], conv_b, conv1_b, ck_b,
        wbig3, wfq, w3b, gcnT, fqbias, fbias, zpage);
    k_upsum<<<dim3(64, 16), 256, 0, stream>>>(x_cur, x_lat, xsum);

    for (int s = 0; s < 3; ++s) {
        { // BIG: split-K=5 (tap-aligned 2048), bf16 partials — r10 proven
            GemmP p{};
            p.A = (s == 0) ? xsum : feat;
            p.B = wbig3 + (long long)s * 256 * 10240; p.ldb = 10240;
            p.Ksub = 2048; p.kSplit = 2048; p.dil = 1 << s;
            p.obf = ftmp; p.oBatch = 16384ll * 256;
            p.zpage = zpage;
            gemm_big<<<dim3(128, 2, 5), 256, 0, stream>>>(p);
        }
        k_combine<<<2048, 256, 0, stream>>>(ftmp, fbias + s * 256, fbuf);
        k_poolcw<<<64, 1024, 0, stream>>>(fbuf, avg_w, max_w, cwb);
        if (s < 2) { // merged: feat = conv1(f)+b+xsum  AND  q = relu(f@ck^T+b)
            GemmP p{};
            p.A = fbuf; p.lda = 256; p.B = wfq; p.ldb = 256;
            p.Ksub = 256; p.bias = fqbias;
            p.res = xsum;
            p.obf = feat; p.obf2 = qbuf;
            gemm_k<64, 64, 0, EPI_FQ><<<dim3(256, 18, 1), 256, 0, stream>>>(p);
        } else {     // q only
            GemmP p{};
            p.A = fbuf; p.lda = 256; p.B = wfq + 1024 * 256; p.ldb = 256;
            p.Ksub = 256;
            p.bias = ck_b; p.obf = qbuf; p.ldo = 128;
            gemm_k<64, 64, 0, EPI_RELU><<<dim3(256, 2, 1), 256, 0, stream>>>(p);
        }
        { // dsum8 partial row-sums of sigmoid((q*cw)_i . q_j); cw folded into A-load
            GemmP p{};
            p.A = qbuf; p.aBatch = 32768; p.lda = 128;
            p.B = qbuf; p.bBatch = 32768; p.ldb = 128;
            p.Ksub = 128; p.dsum = dsum8; p.cw = cwb;
            gemm_k<64, 64, 3, EPI_SIG><<<dim3(4, 4, 64), 256, 0, stream>>>(p);
        }
        k_pscale<<<dim3(2, 64), 256, 0, stream>>>(qbuf, dsum8, dscale, Pt);
        { // XGt[b][c][j] = sum_c' gcnT[c][c'] fbuf_b[j][c']
            GemmP p{};
            p.A = gcnT; p.aBatch = 0;     p.lda = 256;
            p.B = fbuf; p.bBatch = 65536; p.ldb = 256;
            p.Ksub = 256;
            p.obf = xgt; p.oBatch = 65536; p.ldo = 256;
            gemm_k<64, 64, 0, EPI_XG><<<dim3(4, 4, 64), 256, 0, stream>>>(p);
        }
        { // Htn[b][c][m] = -cw[m] * sum_j XGt[c][j] Pt[m][j]
            GemmP p{};
            p.A = xgt; p.aBatch = 65536; p.lda = 256;
            p.B = Pt;  p.bBatch = 32768; p.ldb = 256;
            p.Ksub = 256; p.cw = cwb;
            p.obf = Htn; p.oBatch = 32768; p.ldo = 128;
            gemm_k<64, 64, 0, EPI_NEGCW><<<dim3(4, 2, 64), 256, 0, stream>>>(p);
        }
        { // Y = X + X@G - (d*q)@H : K=384 dual-source -> catb slice
            GemmP p{};
            p.A = fbuf; p.aBatch = 65536; p.lda = 256;
            p.B = gcnT; p.bBatch = 0;     p.ldb = 256;
            p.A2 = qbuf; p.a2Batch = 32768; p.lda2 = 128; p.rscale = dscale;
            p.B2 = Htn;  p.b2Batch = 32768; p.ldb2 = 128;
            p.Ksub = 384;
            p.res = fbuf; p.resBatch = 65536; p.ldres = 256;
            p.obf = catb + s * 256; p.oBatch = 256ll * 768; p.ldo = 768;
            gemm_k<64, 64, 2, EPI_Y><<<dim3(4, 4, 64), 256, 0, stream>>>(p);
        }
    }
    { // out[bb][o][px] = sum_k w3[o][k] cat[px][k] + conv3_b[o]
        GemmP p{};
        p.A = w3b;  p.lda = 768;
        p.B = catb; p.ldb = 768;
        p.Ksub = 768; p.bias = conv3_b; p.of32 = out;
        gemm_k<64, 128, 0, EPI_OUTT><<<dim3(16, 128, 1), 256, 0, stream>>>(p);
    }
}

// Round 13
// 646.393 us; speedup vs baseline: 1.0889x; 1.0695x over previous
//
#include <hip/hip_runtime.h>

typedef unsigned short ushort_t;
typedef unsigned int uint32;
typedef __attribute__((ext_vector_type(8))) unsigned short ushort8;
typedef __attribute__((ext_vector_type(8))) __bf16 bf16x8;
typedef __attribute__((ext_vector_type(4))) float f32x4;

__device__ __forceinline__ ushort_t f2b(float f) {
    union { float f; uint32 u; } v; v.f = f;
    uint32 r = v.u + 0x7fffu + ((v.u >> 16) & 1u);
    return (ushort_t)(r >> 16);
}
__device__ __forceinline__ float b2f(ushort_t b) {
    union { uint32 u; float f; } v; v.u = ((uint32)b) << 16;
    return v.f;
}
__device__ __forceinline__ float sigm(float x) { return 1.f / (1.f + __expf(-x)); }

__device__ __forceinline__ void gload_lds16(const void* g, void* l) {
    __builtin_amdgcn_global_load_lds(
        (__attribute__((address_space(1))) void*)g,
        (__attribute__((address_space(3))) void*)l, 16, 0, 0);
}

// epilogues
constexpr int EPI_RELU  = 1;  // bf16 relu(acc+bias) -> obf (q for s==2)
constexpr int EPI_FQ    = 2;  // merged: col<1024 feat=acc+bias+res; col>=1024 q=relu(acc+bias)
constexpr int EPI_SIG   = 3;  // rowsum sigmoid(acc) -> dsum[(by*2+wc)][z*256+row]
constexpr int EPI_XG    = 4;  // bf16 acc -> obf[z*oB + row*ldo + col]  (XGt)
constexpr int EPI_NEGCW = 5;  // bf16 -acc*cw[z*128+col] -> obf (Htn)
constexpr int EPI_Y     = 6;  // bf16 res + acc -> obf (catb slice)
constexpr int EPI_OUTT  = 7;  // fp32 acc+bias[row]; row=outchan, col=pixel -> NCHW coalesced

struct GemmP {
    const ushort_t* A; const ushort_t* B;
    const ushort_t* A2; const ushort_t* B2;     // AMODE==2 second source (gk >= 256)
    long long aBatch, bBatch, a2Batch, b2Batch;
    int lda, ldb, lda2, ldb2;
    int Ksub, kSplit, dil;
    const float* bias;
    const ushort_t* res; long long resBatch; int ldres;
    ushort_t* obf; long long oBatch; int ldo;
    ushort_t* obf2;
    float* of32;
    const float* cw;
    const float* rscale;   // AMODE==2: per-row scale of A2 (d factor)
    float* dsum;
    const ushort_t* zpage;
};

// ---------------------------------------------------------------------------
// BIG implicit-GEMM (9 dilated conv taps + conv1x1 identity tap), m97-style
// global_load_lds staging, split-K=5 (grid 1280 = 5 blocks/CU = LDS cap),
// 128x128 tile, BK=64. LDS image S[r][g] = G[r][g ^ (r&7)] via pre-swizzled
// per-lane global source; read side applies the same XOR (conflict-free,
// r3-verified: 4.7e7 -> 0). Split-K chunks are tap-aligned (2048 = 2 taps):
// tap geometry + im2col pointers hoist to a per-tap outer loop; inner 16
// K-steps only add kin. OOB rows use an 8KB zero page. bf16 partials.
// r11 lesson: the 256^2 2-deep counted-vmcnt variant REGRESSED (lost the
// 5-blocks/CU cross-block overlap; m196/m230 regime gate). Keep this.
// ---------------------------------------------------------------------------
__global__ __launch_bounds__(256) void gemm_big(GemmP p) {
    __shared__ __align__(16) ushort_t aT[128 * 64];
    __shared__ __align__(16) ushort_t bT[128 * 64];
    const int tid = threadIdx.x;
    const int z = blockIdx.z;
    const int m0 = blockIdx.x * 128, n0 = blockIdx.y * 128;
    const int lane = tid & 63, wid = tid >> 6;
    const int l15 = lane & 15, l16 = lane >> 4;
    const int wr = wid >> 1, wc = wid & 1;
    const int lrow = lane >> 3;
    const int sgran = (lane & 7) ^ lrow;

    int ayy[4], axx[4];
    const ushort_t* aBase[4];
    const ushort_t* bBase[4];
#pragma unroll
    for (int i = 0; i < 4; ++i) {
        int row = wid * 32 + i * 8 + lrow;
        int m = m0 + row;
        int bb = m >> 8;
        ayy[i] = (m >> 4) & 15; axx[i] = m & 15;
        aBase[i] = p.A + (long long)bb * 262144 + sgran * 8;
        bBase[i] = p.B + (long long)(n0 + row) * p.ldb + sgran * 8;
    }

    f32x4 acc[4][4];
#pragma unroll
    for (int i = 0; i < 4; ++i)
#pragma unroll
        for (int j = 0; j < 4; ++j) acc[i][j] = (f32x4){0.f, 0.f, 0.f, 0.f};

    const int gk0 = z * p.kSplit;          // tap-aligned
    const int ntap = p.Ksub >> 10;
    for (int ti = 0; ti < ntap; ++ti) {
        const int tap = (gk0 >> 10) + ti;
        int dy = 0, dx = 0;
        if (tap < 9) { int ky = tap / 3; dy = (ky - 1) * p.dil; dx = (tap - ky * 3 - 1) * p.dil; }
        const ushort_t* gaA[4];
        const ushort_t* gaB[4];
#pragma unroll
        for (int i = 0; i < 4; ++i) {
            int iy = ayy[i] + dy, ix = axx[i] + dx;
            bool ok = ((unsigned)iy < 16u) && ((unsigned)ix < 16u);
            gaA[i] = ok ? (aBase[i] + (((iy << 4) + ix) << 10)) : (p.zpage + sgran * 8);
            gaB[i] = bBase[i] + (tap << 10);
        }
        for (int kk = 0; kk < 16; ++kk) {
            const int kin = kk << 6;
#pragma unroll
            for (int i = 0; i < 4; ++i)
                gload_lds16(gaA[i] + kin, &aT[(wid * 32 + i * 8) * 64]);
#pragma unroll
            for (int i = 0; i < 4; ++i)
                gload_lds16(gaB[i] + kin, &bT[(wid * 32 + i * 8) * 64]);
            asm volatile("s_waitcnt vmcnt(0)" ::: "memory");
            __syncthreads();
#pragma unroll
            for (int ks = 0; ks < 2; ++ks) {
                bf16x8 af[4], bfr[4];
#pragma unroll
                for (int mi = 0; mi < 4; ++mi) {
                    int rr = wr * 64 + mi * 16 + l15;
                    int cc = (ks * 32 + l16 * 8) ^ ((rr & 7) << 3);
                    af[mi] = __builtin_bit_cast(bf16x8, *(const ushort8*)&aT[rr * 64 + cc]);
                }
#pragma unroll
                for (int ni = 0; ni < 4; ++ni) {
                    int rr = wc * 64 + ni * 16 + l15;
                    int cc = (ks * 32 + l16 * 8) ^ ((rr & 7) << 3);
                    bfr[ni] = __builtin_bit_cast(bf16x8, *(const ushort8*)&bT[rr * 64 + cc]);
                }
#pragma unroll
                for (int mi = 0; mi < 4; ++mi)
#pragma unroll
                    for (int ni = 0; ni < 4; ++ni)
                        acc[mi][ni] = __builtin_amdgcn_mfma_f32_16x16x32_bf16(af[mi], bfr[ni], acc[mi][ni], 0, 0, 0);
            }
            __syncthreads();
        }
    }
#pragma unroll
    for (int mi = 0; mi < 4; ++mi)
#pragma unroll
        for (int ni = 0; ni < 4; ++ni) {
            int gcol = n0 + wc * 64 + ni * 16 + l15;
            int growb = m0 + wr * 64 + mi * 16 + l16 * 4;
#pragma unroll
            for (int r = 0; r < 4; ++r)
                p.obf[(long long)z * p.oBatch + (long long)(growb + r) * 256 + gcol] =
                    f2b(acc[mi][ni][r]);
        }
}

// ---------------------------------------------------------------------------
// Generic 4-wave MFMA GEMM body (device fn; LDS passed in so dual-role
// kernels can share one launch): C = A.B^T, bf16 in, fp32 acc.
// AMODE==0: single source. AMODE==2: dual source (gk<256 A/B, gk>=256
// A2/B2 with per-row rscale on A2). AMODE==3: A's K-elems scaled by
// cw[z*128+k] at load.
// ---------------------------------------------------------------------------
template<int BM, int BN, int AMODE, int EPI>
__device__ __forceinline__ void gemm_body(ushort_t* aT, ushort_t* bT,
                                          const GemmP& p, int z) {
    constexpr int APASS = BM / 32, BPASS = BN / 32;
    constexpr int MFRAG = BM / 32, NFRAG = BN / 32;
    const int tid = threadIdx.x;
    const int m0 = blockIdx.x * BM, n0 = blockIdx.y * BN;
    const int lane = tid & 63, wid = tid >> 6;
    const int l15 = lane & 15, l16 = lane >> 4;
    const int wr = wid >> 1, wc = wid & 1;
    const int srow = tid >> 3, scol = (tid & 7) * 8;
    const int swcol = scol ^ ((srow & 7) << 3);

    const ushort_t* aptr[APASS];
    const ushort_t* bptr[BPASS];
    const ushort_t* aptr2[APASS];
    const ushort_t* bptr2[BPASS];
    float rsA[APASS];
#pragma unroll
    for (int pi = 0; pi < APASS; ++pi)
        aptr[pi] = p.A + (long long)z * p.aBatch +
                   (long long)(m0 + pi * 32 + srow) * p.lda + scol;
#pragma unroll
    for (int pi = 0; pi < BPASS; ++pi)
        bptr[pi] = p.B + (long long)z * p.bBatch +
                   (long long)(n0 + pi * 32 + srow) * p.ldb + scol;
    if constexpr (AMODE == 2) {
#pragma unroll
        for (int pi = 0; pi < APASS; ++pi) {
            aptr2[pi] = p.A2 + (long long)z * p.a2Batch +
                        (long long)(m0 + pi * 32 + srow) * p.lda2 + scol;
            rsA[pi] = p.rscale[z * 256 + m0 + pi * 32 + srow];
        }
#pragma unroll
        for (int pi = 0; pi < BPASS; ++pi)
            bptr2[pi] = p.B2 + (long long)z * p.b2Batch +
                        (long long)(n0 + pi * 32 + srow) * p.ldb2 + scol;
    }

    f32x4 acc[MFRAG][NFRAG];
#pragma unroll
    for (int i = 0; i < MFRAG; ++i)
#pragma unroll
        for (int j = 0; j < NFRAG; ++j) acc[i][j] = (f32x4){0.f, 0.f, 0.f, 0.f};

    ushort8 ar[APASS], br[BPASS];
    auto ldg = [&](int gk) {
        if (AMODE == 2 && gk >= 256) {
            int g2 = gk - 256;
#pragma unroll
            for (int pi = 0; pi < APASS; ++pi) {
                ushort8 t8 = *(const ushort8*)(aptr2[pi] + g2);
#pragma unroll
                for (int k = 0; k < 8; ++k) t8[k] = f2b(b2f(t8[k]) * rsA[pi]);
                ar[pi] = t8;
            }
#pragma unroll
            for (int pi = 0; pi < BPASS; ++pi) br[pi] = *(const ushort8*)(bptr2[pi] + g2);
        } else if constexpr (AMODE == 3) {
#pragma unroll
            for (int pi = 0; pi < APASS; ++pi) {
                ushort8 t8 = *(const ushort8*)(aptr[pi] + gk);
#pragma unroll
                for (int k = 0; k < 8; ++k)
                    t8[k] = f2b(b2f(t8[k]) * p.cw[(z << 7) + gk + scol + k]);
                ar[pi] = t8;
            }
#pragma unroll
            for (int pi = 0; pi < BPASS; ++pi) br[pi] = *(const ushort8*)(bptr[pi] + gk);
        } else {
#pragma unroll
            for (int pi = 0; pi < APASS; ++pi) ar[pi] = *(const ushort8*)(aptr[pi] + gk);
#pragma unroll
            for (int pi = 0; pi < BPASS; ++pi) br[pi] = *(const ushort8*)(bptr[pi] + gk);
        }
    };

    const int gk0 = z * p.kSplit;
    ldg(gk0);
    const int iters = p.Ksub >> 6;
    for (int it = 0; it < iters; ++it) {
#pragma unroll
        for (int pi = 0; pi < APASS; ++pi)
            *(ushort8*)&aT[(pi * 32 + srow) * 64 + swcol] = ar[pi];
#pragma unroll
        for (int pi = 0; pi < BPASS; ++pi)
            *(ushort8*)&bT[(pi * 32 + srow) * 64 + swcol] = br[pi];
        __syncthreads();
        if (it + 1 < iters) ldg(gk0 + (it + 1) * 64);
#pragma unroll
        for (int ks = 0; ks < 2; ++ks) {
            bf16x8 af[MFRAG], bfr[NFRAG];
#pragma unroll
            for (int mi = 0; mi < MFRAG; ++mi) {
                int rr = wr * (BM / 2) + mi * 16 + l15;
                int cc = (ks * 32 + l16 * 8) ^ ((rr & 7) << 3);
                af[mi] = __builtin_bit_cast(bf16x8, *(const ushort8*)&aT[rr * 64 + cc]);
            }
#pragma unroll
            for (int ni = 0; ni < NFRAG; ++ni) {
                int rr = wc * (BN / 2) + ni * 16 + l15;
                int cc = (ks * 32 + l16 * 8) ^ ((rr & 7) << 3);
                bfr[ni] = __builtin_bit_cast(bf16x8, *(const ushort8*)&bT[rr * 64 + cc]);
            }
#pragma unroll
            for (int mi = 0; mi < MFRAG; ++mi)
#pragma unroll
                for (int ni = 0; ni < NFRAG; ++ni)
                    acc[mi][ni] = __builtin_amdgcn_mfma_f32_16x16x32_bf16(af[mi], bfr[ni], acc[mi][ni], 0, 0, 0);
        }
        __syncthreads();
    }

    // ---------------- epilogue ----------------
#pragma unroll
    for (int mi = 0; mi < MFRAG; ++mi) {
        if constexpr (EPI == EPI_SIG) {
#pragma unroll
            for (int r = 0; r < 4; ++r) {
                float sv = 0.f;
#pragma unroll
                for (int ni = 0; ni < NFRAG; ++ni) sv += sigm(acc[mi][ni][r]);
                sv += __shfl_xor(sv, 1); sv += __shfl_xor(sv, 2);
                sv += __shfl_xor(sv, 4); sv += __shfl_xor(sv, 8);
                if (l15 == 0) {
                    int grow = m0 + wr * (BM / 2) + mi * 16 + l16 * 4 + r;
                    int q8 = blockIdx.y * 2 + wc;  // disjoint slot -> deterministic
                    p.dsum[q8 * 16384 + z * 256 + grow] = sv;
                }
            }
        } else {
#pragma unroll
            for (int ni = 0; ni < NFRAG; ++ni) {
                int gcol = n0 + wc * (BN / 2) + ni * 16 + l15;
                int growb = m0 + wr * (BM / 2) + mi * 16 + l16 * 4;
#pragma unroll
                for (int r = 0; r < 4; ++r) {
                    int grow = growb + r;
                    float v = acc[mi][ni][r];
                    if constexpr (EPI == EPI_RELU) {
                        v += p.bias[gcol]; v = fmaxf(v, 0.f);
                        p.obf[(long long)grow * p.ldo + gcol] = f2b(v);
                    } else if constexpr (EPI == EPI_FQ) {
                        v += p.bias[gcol];
                        if (gcol < 1024) {   // uniform per tile (1024%BN==0)
                            v += b2f(p.res[(long long)grow * 1024 + gcol]);
                            p.obf[(long long)grow * 1024 + gcol] = f2b(v);
                        } else {
                            v = fmaxf(v, 0.f);
                            p.obf2[(long long)grow * 128 + (gcol - 1024)] = f2b(v);
                        }
                    } else if constexpr (EPI == EPI_XG) {
                        p.obf[(long long)z * p.oBatch + (long long)grow * p.ldo + gcol] = f2b(v);
                    } else if constexpr (EPI == EPI_NEGCW) {
                        v *= -p.cw[z * 128 + gcol];
                        p.obf[(long long)z * p.oBatch + (long long)grow * p.ldo + gcol] = f2b(v);
                    } else if constexpr (EPI == EPI_Y) {
                        v = b2f(p.res[(long long)z * p.resBatch + (long long)grow * p.ldres + gcol]) + v;
                        p.obf[(long long)z * p.oBatch + (long long)grow * p.ldo + gcol] = f2b(v);
                    } else if constexpr (EPI == EPI_OUTT) {
                        v += p.bias[grow];               // row = out-channel
                        int bb = gcol >> 8, px = gcol & 255;
                        p.of32[((long long)bb * 1024 + grow) * 256 + px] = v;  // coalesced over px
                    }
                }
            }
        }
    }
}

template<int BM, int BN, int AMODE, int EPI>
__global__ __launch_bounds__(256) void gemm_k(GemmP p) {
    __shared__ __align__(16) ushort_t aT[BM * 64];
    __shared__ __align__(16) ushort_t bT[BN * 64];
    gemm_body<BM, BN, AMODE, EPI>(aT, bT, p, blockIdx.z);
}

// avg/max pool + channel-weight MLP body (256 threads; LDS reused)
__device__ __forceinline__ void pool_body(void* lds, const ushort_t* f,
                                          const float* aw, const float* mw,
                                          float* cw) {
    float* sa = (float*)lds;
    float* sm = sa + 256;
    int b = blockIdx.x, t = threadIdx.x;
    float s = 0.f, m = -3.4e38f;
    const ushort_t* base = f + (long long)b * 65536 + t;
    for (int px = 0; px < 256; ++px) { float v = b2f(base[px * 256]); s += v; m = fmaxf(m, v); }
    sa[t] = s * (1.f / 256.f);
    sm[t] = m;
    __syncthreads();
    if (t < 128) {
        float s1 = 0.f, s2 = 0.f;
        const float* a = aw + t * 256; const float* w = mw + t * 256;
        for (int c = 0; c < 256; ++c) { s1 += sa[c] * a[c]; s2 += sm[c] * w[c]; }
        s1 = fmaxf(s1, 0.f); s2 = fmaxf(s2, 0.f);
        cw[b * 128 + t] = sigm(s1 + s2);
    }
}

// FQ GEMM (128^2, y<9) + piggybacked poolcw (y==9, x<64) — pool hides
// under the 1152 FQ blocks; both need only fbuf (same dependency level).
__global__ __launch_bounds__(256) void gemm_fqpool(GemmP p, const float* aw,
                                                   const float* mw, float* cw) {
    __shared__ __align__(16) ushort_t aT[128 * 64];
    __shared__ __align__(16) ushort_t bT[128 * 64];
    if (blockIdx.y == 9) {
        if (blockIdx.x < 64) pool_body(aT, p.A, aw, mw, cw);
        return;
    }
    gemm_body<128, 128, 0, EPI_FQ>(aT, bT, p, 0);
}

// q-only GEMM (s==2; 64^2, y<2) + piggybacked poolcw (y==2, x<64)
__global__ __launch_bounds__(256) void gemm_qpool(GemmP p, const float* aw,
                                                  const float* mw, float* cw) {
    __shared__ __align__(16) ushort_t aT[64 * 64];
    __shared__ __align__(16) ushort_t bT[64 * 64];
    if (blockIdx.y == 2) {
        if (blockIdx.x < 64) pool_body(aT, p.A, aw, mw, cw);
        return;
    }
    gemm_body<64, 64, 0, EPI_RELU>(aT, bT, p, 0);
}

// SIG (z<64) and XGt (z>=64) merged — independent after FQ; one dispatch.
__global__ __launch_bounds__(256) void gemm_sigxg(GemmP ps, GemmP px) {
    __shared__ __align__(16) ushort_t aT[64 * 64];
    __shared__ __align__(16) ushort_t bT[64 * 64];
    int z = blockIdx.z;
    if (z < 64) gemm_body<64, 64, 3, EPI_SIG>(aT, bT, ps, z);
    else        gemm_body<64, 64, 0, EPI_XG>(aT, bT, px, z - 64);
}

// ---------------- small kernels ----------------

// combine 5 bf16 split-K partials + bias -> bf16 fbuf
__global__ void k_combine(const ushort_t* __restrict__ t, const float* __restrict__ fbias_s,
                          ushort_t* __restrict__ f) {
    int idx = blockIdx.x * 256 + threadIdx.x;  // x8 elements
    const long long N = 16384ll * 256;
    ushort8 a0 = *(const ushort8*)(t + (long long)idx * 8);
    ushort8 a1 = *(const ushort8*)(t + N + (long long)idx * 8);
    ushort8 a2 = *(const ushort8*)(t + 2 * N + (long long)idx * 8);
    ushort8 a3 = *(const ushort8*)(t + 3 * N + (long long)idx * 8);
    ushort8 a4 = *(const ushort8*)(t + 4 * N + (long long)idx * 8);
    int cb = (idx * 8) & 255;
    ushort8 o;
#pragma unroll
    for (int k = 0; k < 8; ++k)
        o[k] = f2b(b2f(a0[k]) + b2f(a1[k]) + b2f(a2[k]) + b2f(a3[k]) + b2f(a4[k]) + fbias_s[cb + k]);
    *(ushort8*)&f[(long long)idx * 8] = o;
}

// x_sum = x_cur * (1 + bilinear_up2x_align_corners(x_lat)); bf16 [B*256][1024]
__global__ void k_upsum(const float* __restrict__ xc, const float* __restrict__ xl,
                        ushort_t* __restrict__ xs) {
    __shared__ float lat[64 * 64];
    __shared__ ushort_t tile[64 * 258];
    int b = blockIdx.x, c0 = blockIdx.y * 64;
    int t = threadIdx.x;
    for (int i = t; i < 4096; i += 256)
        lat[i] = xl[((long long)(b * 1024 + c0 + (i >> 6))) * 64 + (i & 63)];
    __syncthreads();
    int y = t >> 4, x = t & 15;
    float fy = y * (7.f / 15.f); int y0 = (int)fy; float wy = fy - y0; int y1 = y0 + 1 > 7 ? 7 : y0 + 1;
    float fx = x * (7.f / 15.f); int x0 = (int)fx; float wx = fx - x0; int x1 = x0 + 1 > 7 ? 7 : x0 + 1;
    for (int cc = 0; cc < 64; ++cc) {
        float cur = xc[((long long)(b * 1024 + c0 + cc)) * 256 + t];
        const float* L = &lat[cc * 64];
        float tv = L[y0 * 8 + x0] * (1.f - wx) + L[y0 * 8 + x1] * wx;
        float bv = L[y1 * 8 + x0] * (1.f - wx) + L[y1 * 8 + x1] * wx;
        float up = tv + (bv - tv) * wy;
        tile[cc * 258 + t] = f2b(cur * (1.f + up));
    }
    __syncthreads();
    for (int i = t; i < 16384; i += 256) {
        int px = i >> 6, cc = i & 63;
        xs[((long long)(b * 256 + px)) * 1024 + c0 + cc] = tile[cc * 258 + px];
    }
}

// d = rsqrt(sum of 8 dsum slots); write dscale (f32) + LDS-tiled transposed Pt
__global__ void k_pscale(const ushort_t* __restrict__ q, const float* __restrict__ dsum8,
                         float* __restrict__ dscale, ushort_t* __restrict__ Pt) {
    __shared__ ushort_t t[128][130];
    __shared__ float dd[128];
    int jh = blockIdx.x, b = blockIdx.y;
    int j0 = jh * 128;
    int tid = threadIdx.x;
    if (tid < 128) {
        int pix = b * 256 + j0 + tid;
        float s = 0.f;
#pragma unroll
        for (int qs = 0; qs < 8; ++qs) s += dsum8[qs * 16384 + pix];
        float r = rsqrtf(s);
        dd[tid] = r;
        dscale[pix] = r;
    }
    __syncthreads();
    int jr = tid >> 7, m = tid & 127;
    for (int i = 0; i < 64; ++i) {
        int j = i * 2 + jr;
        long long qi = ((long long)(b * 256 + j0 + j)) * 128 + m;
        t[j][m] = f2b(dd[j] * b2f(q[qi]));
    }
    __syncthreads();
    for (int i = 0; i < 64; ++i) {
        int mm = i * 2 + jr;
        Pt[((long long)b << 15) + (mm << 8) + j0 + m] = t[m][mm];
    }
}

// One-shot weight/bias packing: blocks [0,768) pack wbig for 3 stages via
// LDS; blocks >= 768 grid-stride flat regions:
//   wfq = [conv1_w(1024 rows); ck_w(128 rows)] bf16, w3b, gcnT,
//   fqbias(1152 f32 = conv1_b ++ ck_b), fbias(3x256 f32), zpage.
__global__ void k_packall(const float* r0, const float* r1, const float* r2,
                          const float* convw, const float* c1w, const float* c3w,
                          const float* ckw, const float* gcnw,
                          const float* rb0, const float* rb1, const float* rb2,
                          const float* cb, const float* c1b, const float* ckbias,
                          ushort_t* wbig3, ushort_t* wfq, ushort_t* w3b,
                          ushort_t* gcnT, float* fqbias, float* fbias,
                          ushort_t* zpage) {
    int blk = blockIdx.x, tid = threadIdx.x;
    if (blk < 768) {
        __shared__ float lw[10240];
        int s = blk >> 8, o = blk & 255;
        const float* rate = s == 0 ? r0 : (s == 1 ? r1 : r2);
        for (int i = tid; i < 9216; i += 256) lw[i] = rate[(long long)o * 9216 + i];
        for (int i = tid; i < 1024; i += 256) lw[9216 + i] = convw[(long long)o * 1024 + i];
        __syncthreads();
        ushort_t* dst = wbig3 + (long long)blk * 10240;
        for (int i = tid; i < 10240; i += 256) {
            int tap = i >> 10, ci = i & 1023;
            float v = (tap < 9) ? lw[ci * 9 + tap] : lw[9216 + ci];
            dst[i] = f2b(v);
        }
        return;
    }
    const int R1 = 262144;            // wfq: conv1_w part
    const int R2 = R1 + 32768;        // wfq: ck_w part
    const int R3 = R2 + 786432;       // w3b
    const int R4 = R3 + 65536;        // gcnT
    const int R5 = R4 + 1152;         // fqbias
    const int R6 = R5 + 768;          // fbias
    const int R7 = R6 + 4096;         // zpage
    int base = (blk - 768) * 2048 + tid * 8;
#pragma unroll
    for (int k = 0; k < 8; ++k) {
        int i = base + k;
        if (i >= R7) return;
        if (i < R1) wfq[i] = f2b(c1w[i]);
        else if (i < R2) wfq[i] = f2b(ckw[i - R1]);
        else if (i < R3) w3b[i - R2] = f2b(c3w[i - R2]);
        else if (i < R4) {
            int ii = i - R3; int c2 = ii >> 8, c1 = ii & 255;
            gcnT[ii] = f2b(gcnw[c1 * 256 + c2]);
        } else if (i < R5) {
            int ii = i - R4;
            fqbias[ii] = (ii < 1024) ? c1b[ii] : ckbias[ii - 1024];
        } else if (i < R6) {
            int ii = i - R5; int s = ii >> 8, t = ii & 255;
            const float* rb = s == 0 ? rb0 : (s == 1 ? rb1 : rb2);
            fbias[ii] = rb[t] + cb[t];
        } else {
            zpage[i - R6] = 0;
        }
    }
}

__global__ void k_sentinel(float* o, int n, float v) {
    int i = blockIdx.x * 256 + threadIdx.x; if (i < n) o[i] = v;
}

// ---------------- launch ----------------
extern "C" void kernel_launch(void* const* d_in, const int* in_sizes, int n_in,
                              void* d_out, int out_size, void* d_ws, size_t ws_size,
                              hipStream_t stream) {
    const float* x_cur  = (const float*)d_in[0];
    const float* x_lat  = (const float*)d_in[1];
    const float* conv_w = (const float*)d_in[2];
    const float* conv_b = (const float*)d_in[3];
    const float* conv1_w = (const float*)d_in[4];
    const float* conv1_b = (const float*)d_in[5];
    const float* conv3_w = (const float*)d_in[6];
    const float* conv3_b = (const float*)d_in[7];
    const float* rate_w[3] = {(const float*)d_in[8], (const float*)d_in[10], (const float*)d_in[12]};
    const float* rate_b[3] = {(const float*)d_in[9], (const float*)d_in[11], (const float*)d_in[13]};
    const float* ck_w  = (const float*)d_in[14];
    const float* ck_b  = (const float*)d_in[15];
    const float* avg_w = (const float*)d_in[16];
    const float* max_w = (const float*)d_in[17];
    const float* gcn_w = (const float*)d_in[18];
    float* out = (float*)d_out;

    char* w = (char*)d_ws;
    auto take = [&](size_t bytes) { void* p = (void*)w; w += (bytes + 255) & ~(size_t)255; return p; };
    ushort_t* xsum   = (ushort_t*)take(16384ll * 1024 * 2);    // 33.55MB
    ushort_t* feat   = (ushort_t*)take(16384ll * 1024 * 2);    // 33.55MB
    ushort_t* fbuf   = (ushort_t*)take(16384ll * 256 * 2);     // 8.39MB
    ushort_t* xgt    = (ushort_t*)take(64ll * 256 * 256 * 2);  // 8.39MB
    ushort_t* qbuf   = (ushort_t*)take(16384ll * 128 * 2);     // 4.19MB
    ushort_t* Pt     = (ushort_t*)take(64ll * 128 * 256 * 2);  // 4.19MB
    ushort_t* Htn    = (ushort_t*)take(64ll * 256 * 128 * 2);  // 4.19MB
    ushort_t* wbig3  = (ushort_t*)take(3ll * 256 * 10240 * 2); // 15.73MB
    ushort_t* wfq    = (ushort_t*)take(1152ll * 256 * 2);      // conv1_w ++ ck_w
    ushort_t* w3b    = (ushort_t*)take(1024ll * 768 * 2);
    ushort_t* gcnT   = (ushort_t*)take(256ll * 256 * 2);
    ushort_t* zpage  = (ushort_t*)take(8192);                  // 4096 ushorts, zeroed
    float*    fqbias = (float*)take(1152 * 4);
    float*    fbias  = (float*)take(3 * 256 * 4);
    float*    cwb    = (float*)take(64 * 128 * 4);
    float*    dscale = (float*)take(64 * 256 * 4);
    float*    dsum8  = (float*)take(8ll * 64 * 256 * 4);
    ushort_t* catb   = (ushort_t*)take(16384ll * 768 * 2);     // 25.17MB
    ushort_t* ftmp   = (ushort_t*)take(5ll * 16384 * 256 * 2); // 41.94MB (5 splits)
    size_t need = (size_t)(w - (char*)d_ws);                   // ~182MB

    if (need > ws_size) {
        float v = 1.0e6f + (float)(ws_size >> 20);
        k_sentinel<<<(out_size + 255) / 256, 256, 0, stream>>>(out, out_size, v);
        return;
    }

    k_packall<<<768 + 563, 256, 0, stream>>>(
        rate_w[0], rate_w[1], rate_w[2], conv_w, conv1_w, conv3_w, ck_w, gcn_w,
        rate_b[0], rate_b[1], rate_b[2], conv_b, conv1_b, ck_b,
        wbig3, wfq, w3b, gcnT, fqbias, fbias, zpage);
    k_upsum<<<dim3(64, 16), 256, 0, stream>>>(x_cur, x_lat, xsum);

    for (int s = 0; s < 3; ++s) {
        { // BIG: split-K=5 (tap-aligned 2048), bf16 partials — r10 proven
            GemmP p{};
            p.A = (s == 0) ? xsum : feat;
            p.B = wbig3 + (long long)s * 256 * 10240; p.ldb = 10240;
            p.Ksub = 2048; p.kSplit = 2048; p.dil = 1 << s;
            p.obf = ftmp; p.oBatch = 16384ll * 256;
            p.zpage = zpage;
            gemm_big<<<dim3(128, 2, 5), 256, 0, stream>>>(p);
        }
        k_combine<<<2048, 256, 0, stream>>>(ftmp, fbias + s * 256, fbuf);
        if (s < 2) { // merged: feat+q GEMM (128^2) with piggybacked poolcw
            GemmP p{};
            p.A = fbuf; p.lda = 256; p.B = wfq; p.ldb = 256;
            p.Ksub = 256; p.bias = fqbias;
            p.res = xsum;
            p.obf = feat; p.obf2 = qbuf;
            gemm_fqpool<<<dim3(128, 10, 1), 256, 0, stream>>>(p, avg_w, max_w, cwb);
        } else {     // q only + piggybacked poolcw
            GemmP p{};
            p.A = fbuf; p.lda = 256; p.B = wfq + 1024 * 256; p.ldb = 256;
            p.Ksub = 256;
            p.bias = ck_b; p.obf = qbuf; p.ldo = 128;
            gemm_qpool<<<dim3(256, 3, 1), 256, 0, stream>>>(p, avg_w, max_w, cwb);
        }
        { // merged dispatch: SIG (z<64) + XGt (z>=64)
            GemmP ps{};
            ps.A = qbuf; ps.aBatch = 32768; ps.lda = 128;
            ps.B = qbuf; ps.bBatch = 32768; ps.ldb = 128;
            ps.Ksub = 128; ps.dsum = dsum8; ps.cw = cwb;
            GemmP px{};
            px.A = gcnT; px.aBatch = 0;     px.lda = 256;
            px.B = fbuf; px.bBatch = 65536; px.ldb = 256;
            px.Ksub = 256;
            px.obf = xgt; px.oBatch = 65536; px.ldo = 256;
            gemm_sigxg<<<dim3(4, 4, 128), 256, 0, stream>>>(ps, px);
        }
        k_pscale<<<dim3(2, 64), 256, 0, stream>>>(qbuf, dsum8, dscale, Pt);
        { // Htn[b][c][m] = -cw[m] * sum_j XGt[c][j] Pt[m][j]
            GemmP p{};
            p.A = xgt; p.aBatch = 65536; p.lda = 256;
            p.B = Pt;  p.bBatch = 32768; p.ldb = 256;
            p.Ksub = 256; p.cw = cwb;
            p.obf = Htn; p.oBatch = 32768; p.ldo = 128;
            gemm_k<64, 64, 0, EPI_NEGCW><<<dim3(4, 2, 64), 256, 0, stream>>>(p);
        }
        { // Y = X + X@G - (d*q)@H : K=384 dual-source -> catb slice
            GemmP p{};
            p.A = fbuf; p.aBatch = 65536; p.lda = 256;
            p.B = gcnT; p.bBatch = 0;     p.ldb = 256;
            p.A2 = qbuf; p.a2Batch = 32768; p.lda2 = 128; p.rscale = dscale;
            p.B2 = Htn;  p.b2Batch = 32768; p.ldb2 = 128;
            p.Ksub = 384;
            p.res = fbuf; p.resBatch = 65536; p.ldres = 256;
            p.obf = catb + s * 256; p.oBatch = 256ll * 768; p.ldo = 768;
            gemm_k<64, 64, 2, EPI_Y><<<dim3(4, 4, 64), 256, 0, stream>>>(p);
        }
    }
    { // out[bb][o][px] = sum_k w3[o][k] cat[px][k] + conv3_b[o]
        GemmP p{};
        p.A = w3b;  p.lda = 768;
        p.B = catb; p.ldb = 768;
        p.Ksub = 768; p.bias = conv3_b; p.of32 = out;
        gemm_k<64, 128, 0, EPI_OUTT><<<dim3(16, 128, 1), 256, 0, stream>>>(p);
    }
}

// Round 14
// 625.996 us; speedup vs baseline: 1.1244x; 1.0326x over previous
//
#include <hip/hip_runtime.h>

typedef unsigned short ushort_t;
typedef unsigned int uint32;
typedef __attribute__((ext_vector_type(8))) unsigned short ushort8;
typedef __attribute__((ext_vector_type(8))) __bf16 bf16x8;
typedef __attribute__((ext_vector_type(4))) float f32x4;

__device__ __forceinline__ ushort_t f2b(float f) {
    union { float f; uint32 u; } v; v.f = f;
    uint32 r = v.u + 0x7fffu + ((v.u >> 16) & 1u);
    return (ushort_t)(r >> 16);
}
__device__ __forceinline__ float b2f(ushort_t b) {
    union { uint32 u; float f; } v; v.u = ((uint32)b) << 16;
    return v.f;
}
__device__ __forceinline__ float sigm(float x) { return 1.f / (1.f + __expf(-x)); }

__device__ __forceinline__ void gload_lds16(const void* g, void* l) {
    __builtin_amdgcn_global_load_lds(
        (__attribute__((address_space(1))) void*)g,
        (__attribute__((address_space(3))) void*)l, 16, 0, 0);
}

// epilogues
constexpr int EPI_RELU  = 1;  // bf16 relu(acc+bias) -> obf (q for s==2)
constexpr int EPI_FQ    = 2;  // merged: col<1024 feat=acc+bias+res; col>=1024 q=relu(acc+bias)
constexpr int EPI_SIG   = 3;  // rowsum sigmoid(acc) -> dsum[(by*2+wc)][z*256+row]
constexpr int EPI_XG    = 4;  // bf16 acc -> obf[z*oB + row*ldo + col]  (XGt)
constexpr int EPI_NEGCW = 5;  // bf16 -acc*cw[z*128+col] -> obf (Htn)
constexpr int EPI_Y     = 6;  // bf16 res + acc -> obf (catb slice)
constexpr int EPI_OUTT  = 7;  // fp32 acc+bias[row]; row=outchan, col=pixel -> NCHW coalesced

struct GemmP {
    const ushort_t* A; const ushort_t* B;
    const ushort_t* A2; const ushort_t* B2;     // AMODE==2 second source (gk >= 256)
    long long aBatch, bBatch, a2Batch, b2Batch;
    int lda, ldb, lda2, ldb2;
    int Ksub, kSplit, dil;
    const float* bias;
    const ushort_t* res; long long resBatch; int ldres;
    ushort_t* obf; long long oBatch; int ldo;
    ushort_t* obf2;
    float* of32;
    const float* cw;
    const float* rscale;   // AMODE==2: per-row scale of A2 (d factor)
    float* dsum;
    const ushort_t* zpage;
};

// ---------------------------------------------------------------------------
// BIG implicit-GEMM body (9 dilated conv taps + conv1x1 identity tap),
// m97-style global_load_lds staging, split-K=5, 128x128 tile, BK=64.
// LDS image S[r][g] = G[r][g ^ (r&7)] via pre-swizzled per-lane source;
// reads apply the same XOR (conflict-free, r3-verified). Tap-aligned split-K
// chunks (2048 = 2 taps): tap geometry hoisted to per-tap outer loop. OOB
// rows use an 8KB zero page. bf16 partials. r11 lesson: 256^2 counted-vmcnt
// variant REGRESSED (lost 5-blocks/CU cross-block overlap). Keep this.
// ---------------------------------------------------------------------------
__device__ __forceinline__ void big_body(ushort_t* aT, ushort_t* bT,
                                         const GemmP& p, int bx, int by, int z) {
    const int tid = threadIdx.x;
    const int m0 = bx * 128, n0 = by * 128;
    const int lane = tid & 63, wid = tid >> 6;
    const int l15 = lane & 15, l16 = lane >> 4;
    const int wr = wid >> 1, wc = wid & 1;
    const int lrow = lane >> 3;
    const int sgran = (lane & 7) ^ lrow;

    int ayy[4], axx[4];
    const ushort_t* aBase[4];
    const ushort_t* bBase[4];
#pragma unroll
    for (int i = 0; i < 4; ++i) {
        int row = wid * 32 + i * 8 + lrow;
        int m = m0 + row;
        int bb = m >> 8;
        ayy[i] = (m >> 4) & 15; axx[i] = m & 15;
        aBase[i] = p.A + (long long)bb * 262144 + sgran * 8;
        bBase[i] = p.B + (long long)(n0 + row) * p.ldb + sgran * 8;
    }

    f32x4 acc[4][4];
#pragma unroll
    for (int i = 0; i < 4; ++i)
#pragma unroll
        for (int j = 0; j < 4; ++j) acc[i][j] = (f32x4){0.f, 0.f, 0.f, 0.f};

    const int gk0 = z * p.kSplit;          // tap-aligned
    const int ntap = p.Ksub >> 10;
    for (int ti = 0; ti < ntap; ++ti) {
        const int tap = (gk0 >> 10) + ti;
        int dy = 0, dx = 0;
        if (tap < 9) { int ky = tap / 3; dy = (ky - 1) * p.dil; dx = (tap - ky * 3 - 1) * p.dil; }
        const ushort_t* gaA[4];
        const ushort_t* gaB[4];
#pragma unroll
        for (int i = 0; i < 4; ++i) {
            int iy = ayy[i] + dy, ix = axx[i] + dx;
            bool ok = ((unsigned)iy < 16u) && ((unsigned)ix < 16u);
            gaA[i] = ok ? (aBase[i] + (((iy << 4) + ix) << 10)) : (p.zpage + sgran * 8);
            gaB[i] = bBase[i] + (tap << 10);
        }
        for (int kk = 0; kk < 16; ++kk) {
            const int kin = kk << 6;
#pragma unroll
            for (int i = 0; i < 4; ++i)
                gload_lds16(gaA[i] + kin, &aT[(wid * 32 + i * 8) * 64]);
#pragma unroll
            for (int i = 0; i < 4; ++i)
                gload_lds16(gaB[i] + kin, &bT[(wid * 32 + i * 8) * 64]);
            asm volatile("s_waitcnt vmcnt(0)" ::: "memory");
            __syncthreads();
#pragma unroll
            for (int ks = 0; ks < 2; ++ks) {
                bf16x8 af[4], bfr[4];
#pragma unroll
                for (int mi = 0; mi < 4; ++mi) {
                    int rr = wr * 64 + mi * 16 + l15;
                    int cc = (ks * 32 + l16 * 8) ^ ((rr & 7) << 3);
                    af[mi] = __builtin_bit_cast(bf16x8, *(const ushort8*)&aT[rr * 64 + cc]);
                }
#pragma unroll
                for (int ni = 0; ni < 4; ++ni) {
                    int rr = wc * 64 + ni * 16 + l15;
                    int cc = (ks * 32 + l16 * 8) ^ ((rr & 7) << 3);
                    bfr[ni] = __builtin_bit_cast(bf16x8, *(const ushort8*)&bT[rr * 64 + cc]);
                }
#pragma unroll
                for (int mi = 0; mi < 4; ++mi)
#pragma unroll
                    for (int ni = 0; ni < 4; ++ni)
                        acc[mi][ni] = __builtin_amdgcn_mfma_f32_16x16x32_bf16(af[mi], bfr[ni], acc[mi][ni], 0, 0, 0);
            }
            __syncthreads();
        }
    }
#pragma unroll
    for (int mi = 0; mi < 4; ++mi)
#pragma unroll
        for (int ni = 0; ni < 4; ++ni) {
            int gcol = n0 + wc * 64 + ni * 16 + l15;
            int growb = m0 + wr * 64 + mi * 16 + l16 * 4;
#pragma unroll
            for (int r = 0; r < 4; ++r)
                p.obf[(long long)z * p.oBatch + (long long)(growb + r) * 256 + gcol] =
                    f2b(acc[mi][ni][r]);
        }
}

// ---------------------------------------------------------------------------
// Generic 4-wave MFMA GEMM body (explicit bx/by/z so merged kernels can
// remap grid planes to roles): C = A.B^T, bf16 in, fp32 acc.
// AMODE==0: single source. AMODE==2: dual source. AMODE==3: A K-scaled by cw.
// ---------------------------------------------------------------------------
template<int BM, int BN, int AMODE, int EPI>
__device__ __forceinline__ void gemm_body(ushort_t* aT, ushort_t* bT,
                                          const GemmP& p, int bx, int by, int z) {
    constexpr int APASS = BM / 32, BPASS = BN / 32;
    constexpr int MFRAG = BM / 32, NFRAG = BN / 32;
    const int tid = threadIdx.x;
    const int m0 = bx * BM, n0 = by * BN;
    const int lane = tid & 63, wid = tid >> 6;
    const int l15 = lane & 15, l16 = lane >> 4;
    const int wr = wid >> 1, wc = wid & 1;
    const int srow = tid >> 3, scol = (tid & 7) * 8;
    const int swcol = scol ^ ((srow & 7) << 3);

    const ushort_t* aptr[APASS];
    const ushort_t* bptr[BPASS];
    const ushort_t* aptr2[APASS];
    const ushort_t* bptr2[BPASS];
    float rsA[APASS];
#pragma unroll
    for (int pi = 0; pi < APASS; ++pi)
        aptr[pi] = p.A + (long long)z * p.aBatch +
                   (long long)(m0 + pi * 32 + srow) * p.lda + scol;
#pragma unroll
    for (int pi = 0; pi < BPASS; ++pi)
        bptr[pi] = p.B + (long long)z * p.bBatch +
                   (long long)(n0 + pi * 32 + srow) * p.ldb + scol;
    if constexpr (AMODE == 2) {
#pragma unroll
        for (int pi = 0; pi < APASS; ++pi) {
            aptr2[pi] = p.A2 + (long long)z * p.a2Batch +
                        (long long)(m0 + pi * 32 + srow) * p.lda2 + scol;
            rsA[pi] = p.rscale[z * 256 + m0 + pi * 32 + srow];
        }
#pragma unroll
        for (int pi = 0; pi < BPASS; ++pi)
            bptr2[pi] = p.B2 + (long long)z * p.b2Batch +
                        (long long)(n0 + pi * 32 + srow) * p.ldb2 + scol;
    }

    f32x4 acc[MFRAG][NFRAG];
#pragma unroll
    for (int i = 0; i < MFRAG; ++i)
#pragma unroll
        for (int j = 0; j < NFRAG; ++j) acc[i][j] = (f32x4){0.f, 0.f, 0.f, 0.f};

    ushort8 ar[APASS], br[BPASS];
    auto ldg = [&](int gk) {
        if (AMODE == 2 && gk >= 256) {
            int g2 = gk - 256;
#pragma unroll
            for (int pi = 0; pi < APASS; ++pi) {
                ushort8 t8 = *(const ushort8*)(aptr2[pi] + g2);
#pragma unroll
                for (int k = 0; k < 8; ++k) t8[k] = f2b(b2f(t8[k]) * rsA[pi]);
                ar[pi] = t8;
            }
#pragma unroll
            for (int pi = 0; pi < BPASS; ++pi) br[pi] = *(const ushort8*)(bptr2[pi] + g2);
        } else if constexpr (AMODE == 3) {
#pragma unroll
            for (int pi = 0; pi < APASS; ++pi) {
                ushort8 t8 = *(const ushort8*)(aptr[pi] + gk);
#pragma unroll
                for (int k = 0; k < 8; ++k)
                    t8[k] = f2b(b2f(t8[k]) * p.cw[(z << 7) + gk + scol + k]);
                ar[pi] = t8;
            }
#pragma unroll
            for (int pi = 0; pi < BPASS; ++pi) br[pi] = *(const ushort8*)(bptr[pi] + gk);
        } else {
#pragma unroll
            for (int pi = 0; pi < APASS; ++pi) ar[pi] = *(const ushort8*)(aptr[pi] + gk);
#pragma unroll
            for (int pi = 0; pi < BPASS; ++pi) br[pi] = *(const ushort8*)(bptr[pi] + gk);
        }
    };

    const int gk0 = z * p.kSplit;
    ldg(gk0);
    const int iters = p.Ksub >> 6;
    for (int it = 0; it < iters; ++it) {
#pragma unroll
        for (int pi = 0; pi < APASS; ++pi)
            *(ushort8*)&aT[(pi * 32 + srow) * 64 + swcol] = ar[pi];
#pragma unroll
        for (int pi = 0; pi < BPASS; ++pi)
            *(ushort8*)&bT[(pi * 32 + srow) * 64 + swcol] = br[pi];
        __syncthreads();
        if (it + 1 < iters) ldg(gk0 + (it + 1) * 64);
#pragma unroll
        for (int ks = 0; ks < 2; ++ks) {
            bf16x8 af[MFRAG], bfr[NFRAG];
#pragma unroll
            for (int mi = 0; mi < MFRAG; ++mi) {
                int rr = wr * (BM / 2) + mi * 16 + l15;
                int cc = (ks * 32 + l16 * 8) ^ ((rr & 7) << 3);
                af[mi] = __builtin_bit_cast(bf16x8, *(const ushort8*)&aT[rr * 64 + cc]);
            }
#pragma unroll
            for (int ni = 0; ni < NFRAG; ++ni) {
                int rr = wc * (BN / 2) + ni * 16 + l15;
                int cc = (ks * 32 + l16 * 8) ^ ((rr & 7) << 3);
                bfr[ni] = __builtin_bit_cast(bf16x8, *(const ushort8*)&bT[rr * 64 + cc]);
            }
#pragma unroll
            for (int mi = 0; mi < MFRAG; ++mi)
#pragma unroll
                for (int ni = 0; ni < NFRAG; ++ni)
                    acc[mi][ni] = __builtin_amdgcn_mfma_f32_16x16x32_bf16(af[mi], bfr[ni], acc[mi][ni], 0, 0, 0);
        }
        __syncthreads();
    }

    // ---------------- epilogue ----------------
#pragma unroll
    for (int mi = 0; mi < MFRAG; ++mi) {
        if constexpr (EPI == EPI_SIG) {
#pragma unroll
            for (int r = 0; r < 4; ++r) {
                float sv = 0.f;
#pragma unroll
                for (int ni = 0; ni < NFRAG; ++ni) sv += sigm(acc[mi][ni][r]);
                sv += __shfl_xor(sv, 1); sv += __shfl_xor(sv, 2);
                sv += __shfl_xor(sv, 4); sv += __shfl_xor(sv, 8);
                if (l15 == 0) {
                    int grow = m0 + wr * (BM / 2) + mi * 16 + l16 * 4 + r;
                    int q8 = by * 2 + wc;  // disjoint slot -> deterministic
                    p.dsum[q8 * 16384 + z * 256 + grow] = sv;
                }
            }
        } else {
#pragma unroll
            for (int ni = 0; ni < NFRAG; ++ni) {
                int gcol = n0 + wc * (BN / 2) + ni * 16 + l15;
                int growb = m0 + wr * (BM / 2) + mi * 16 + l16 * 4;
#pragma unroll
                for (int r = 0; r < 4; ++r) {
                    int grow = growb + r;
                    float v = acc[mi][ni][r];
                    if constexpr (EPI == EPI_RELU) {
                        v += p.bias[gcol]; v = fmaxf(v, 0.f);
                        p.obf[(long long)grow * p.ldo + gcol] = f2b(v);
                    } else if constexpr (EPI == EPI_FQ) {
                        v += p.bias[gcol];
                        if (gcol < 1024) {   // uniform per tile (1024%BN==0)
                            v += b2f(p.res[(long long)grow * 1024 + gcol]);
                            p.obf[(long long)grow * 1024 + gcol] = f2b(v);
                        } else {
                            v = fmaxf(v, 0.f);
                            p.obf2[(long long)grow * 128 + (gcol - 1024)] = f2b(v);
                        }
                    } else if constexpr (EPI == EPI_XG) {
                        p.obf[(long long)z * p.oBatch + (long long)grow * p.ldo + gcol] = f2b(v);
                    } else if constexpr (EPI == EPI_NEGCW) {
                        v *= -p.cw[z * 128 + gcol];
                        p.obf[(long long)z * p.oBatch + (long long)grow * p.ldo + gcol] = f2b(v);
                    } else if constexpr (EPI == EPI_Y) {
                        v = b2f(p.res[(long long)z * p.resBatch + (long long)grow * p.ldres + gcol]) + v;
                        p.obf[(long long)z * p.oBatch + (long long)grow * p.ldo + gcol] = f2b(v);
                    } else if constexpr (EPI == EPI_OUTT) {
                        v += p.bias[grow];               // row = out-channel
                        int bb = gcol >> 8, px = gcol & 255;
                        p.of32[((long long)bb * 1024 + grow) * 256 + px] = v;  // coalesced over px
                    }
                }
            }
        }
    }
}

template<int BM, int BN, int AMODE, int EPI>
__global__ __launch_bounds__(256) void gemm_k(GemmP p) {
    __shared__ __align__(16) ushort_t aT[BM * 64];
    __shared__ __align__(16) ushort_t bT[BN * 64];
    gemm_body<BM, BN, AMODE, EPI>(aT, bT, p, blockIdx.x, blockIdx.y, blockIdx.z);
}

// avg/max pool + channel-weight MLP body (256 threads; LDS reused)
__device__ __forceinline__ void pool_body(void* lds, int b, const ushort_t* f,
                                          const float* aw, const float* mw,
                                          float* cw) {
    float* sa = (float*)lds;
    float* sm = sa + 256;
    int t = threadIdx.x;
    float s = 0.f, m = -3.4e38f;
    const ushort_t* base = f + (long long)b * 65536 + t;
    for (int px = 0; px < 256; ++px) { float v = b2f(base[px * 256]); s += v; m = fmaxf(m, v); }
    sa[t] = s * (1.f / 256.f);
    sm[t] = m;
    __syncthreads();
    if (t < 128) {
        float s1 = 0.f, s2 = 0.f;
        const float* a = aw + t * 256; const float* w = mw + t * 256;
        for (int c = 0; c < 256; ++c) { s1 += sa[c] * a[c]; s2 += sm[c] * w[c]; }
        s1 = fmaxf(s1, 0.f); s2 = fmaxf(s2, 0.f);
        cw[b * 128 + t] = sigm(s1 + s2);
    }
}

// BIG (z<5) ∥ sigxg_{prev} (z in 5..12) ∥ Y_{prev2} (z in 13..16).
// Grid z-dim selects how many roles run: 5 = BIG only, 13 = +sigxg, 17 = +Y.
__global__ __launch_bounds__(256) void k_big_sig_y(GemmP pb, GemmP ps, GemmP px,
                                                   GemmP py) {
    __shared__ __align__(16) ushort_t lds[2 * 128 * 64];
    int z = blockIdx.z;
    if (z < 5) { big_body(lds, lds + 8192, pb, blockIdx.x, blockIdx.y, z); return; }
    if (z < 13) {
        int flat = (z - 5) * 256 + blockIdx.y * 128 + blockIdx.x;  // 0..2047
        int bx = flat & 3, by = (flat >> 2) & 3, bz = flat >> 4;
        if (bz < 64) gemm_body<64, 64, 3, EPI_SIG>(lds, lds + 4096, ps, bx, by, bz);
        else         gemm_body<64, 64, 0, EPI_XG>(lds, lds + 4096, px, bx, by, bz - 64);
        return;
    }
    int flat = (z - 13) * 256 + blockIdx.y * 128 + blockIdx.x;     // 0..1023
    gemm_body<64, 64, 2, EPI_Y>(lds, lds + 4096, py, flat & 3, (flat >> 2) & 3, flat >> 4);
}

// FQ GEMM (y<9, 128^2) ∥ poolcw (y==9, x<64) ∥ Htn_{prev} (y in 10..13).
// Grid y-dim 10 = FQ+pool only; 14 = +Htn.
__global__ __launch_bounds__(256) void k_fqpool_htn(GemmP pf, GemmP ph,
                                                    const float* aw, const float* mw,
                                                    float* cw) {
    __shared__ __align__(16) ushort_t lds[2 * 128 * 64];
    int y = blockIdx.y;
    if (y < 9) { gemm_body<128, 128, 0, EPI_FQ>(lds, lds + 8192, pf, blockIdx.x, y, 0); return; }
    if (y == 9) { if (blockIdx.x < 64) pool_body(lds, blockIdx.x, pf.A, aw, mw, cw); return; }
    int flat = (y - 10) * 128 + blockIdx.x;   // 0..511
    gemm_body<64, 64, 0, EPI_NEGCW>(lds, lds + 4096, ph, flat & 3, (flat >> 2) & 1, flat >> 3);
}

// q-only GEMM (y<2, 64^2) ∥ poolcw (y==2) ∥ Htn_{prev} (y in 3..4)
__global__ __launch_bounds__(256) void k_qpool_htn(GemmP pq, GemmP ph,
                                                   const float* aw, const float* mw,
                                                   float* cw) {
    __shared__ __align__(16) ushort_t lds[2 * 64 * 64];
    int y = blockIdx.y;
    if (y < 2) { gemm_body<64, 64, 0, EPI_RELU>(lds, lds + 4096, pq, blockIdx.x, y, 0); return; }
    if (y == 2) { if (blockIdx.x < 64) pool_body(lds, blockIdx.x, pq.A, aw, mw, cw); return; }
    int flat = (y - 3) * 256 + blockIdx.x;    // 0..511
    gemm_body<64, 64, 0, EPI_NEGCW>(lds, lds + 4096, ph, flat & 3, (flat >> 2) & 1, flat >> 3);
}

// sigxg (z<128) ∥ Y_{prev} (z in 128..191)
__global__ __launch_bounds__(256) void k_sigxg_y(GemmP ps, GemmP px, GemmP py) {
    __shared__ __align__(16) ushort_t aT[64 * 64];
    __shared__ __align__(16) ushort_t bT[64 * 64];
    int z = blockIdx.z;
    if (z < 64)       gemm_body<64, 64, 3, EPI_SIG>(aT, bT, ps, blockIdx.x, blockIdx.y, z);
    else if (z < 128) gemm_body<64, 64, 0, EPI_XG>(aT, bT, px, blockIdx.x, blockIdx.y, z - 64);
    else              gemm_body<64, 64, 2, EPI_Y>(aT, bT, py, blockIdx.x, blockIdx.y, z - 128);
}

// ---------------- small kernels ----------------

// combine 5 bf16 split-K partials + bias -> bf16 fbuf
__global__ void k_combine(const ushort_t* __restrict__ t, const float* __restrict__ fbias_s,
                          ushort_t* __restrict__ f) {
    int idx = blockIdx.x * 256 + threadIdx.x;  // x8 elements
    const long long N = 16384ll * 256;
    ushort8 a0 = *(const ushort8*)(t + (long long)idx * 8);
    ushort8 a1 = *(const ushort8*)(t + N + (long long)idx * 8);
    ushort8 a2 = *(const ushort8*)(t + 2 * N + (long long)idx * 8);
    ushort8 a3 = *(const ushort8*)(t + 3 * N + (long long)idx * 8);
    ushort8 a4 = *(const ushort8*)(t + 4 * N + (long long)idx * 8);
    int cb = (idx * 8) & 255;
    ushort8 o;
#pragma unroll
    for (int k = 0; k < 8; ++k)
        o[k] = f2b(b2f(a0[k]) + b2f(a1[k]) + b2f(a2[k]) + b2f(a3[k]) + b2f(a4[k]) + fbias_s[cb + k]);
    *(ushort8*)&f[(long long)idx * 8] = o;
}

// x_sum = x_cur * (1 + bilinear_up2x_align_corners(x_lat)); bf16 [B*256][1024]
__global__ void k_upsum(const float* __restrict__ xc, const float* __restrict__ xl,
                        ushort_t* __restrict__ xs) {
    __shared__ float lat[64 * 64];
    __shared__ ushort_t tile[64 * 258];
    int b = blockIdx.x, c0 = blockIdx.y * 64;
    int t = threadIdx.x;
    for (int i = t; i < 4096; i += 256)
        lat[i] = xl[((long long)(b * 1024 + c0 + (i >> 6))) * 64 + (i & 63)];
    __syncthreads();
    int y = t >> 4, x = t & 15;
    float fy = y * (7.f / 15.f); int y0 = (int)fy; float wy = fy - y0; int y1 = y0 + 1 > 7 ? 7 : y0 + 1;
    float fx = x * (7.f / 15.f); int x0 = (int)fx; float wx = fx - x0; int x1 = x0 + 1 > 7 ? 7 : x0 + 1;
    for (int cc = 0; cc < 64; ++cc) {
        float cur = xc[((long long)(b * 1024 + c0 + cc)) * 256 + t];
        const float* L = &lat[cc * 64];
        float tv = L[y0 * 8 + x0] * (1.f - wx) + L[y0 * 8 + x1] * wx;
        float bv = L[y1 * 8 + x0] * (1.f - wx) + L[y1 * 8 + x1] * wx;
        float up = tv + (bv - tv) * wy;
        tile[cc * 258 + t] = f2b(cur * (1.f + up));
    }
    __syncthreads();
    for (int i = t; i < 16384; i += 256) {
        int px = i >> 6, cc = i & 63;
        xs[((long long)(b * 256 + px)) * 1024 + c0 + cc] = tile[cc * 258 + px];
    }
}

// d = rsqrt(sum of 8 dsum slots); write dscale (f32) + LDS-tiled transposed Pt
__global__ void k_pscale(const ushort_t* __restrict__ q, const float* __restrict__ dsum8,
                         float* __restrict__ dscale, ushort_t* __restrict__ Pt) {
    __shared__ ushort_t t[128][130];
    __shared__ float dd[128];
    int jh = blockIdx.x, b = blockIdx.y;
    int j0 = jh * 128;
    int tid = threadIdx.x;
    if (tid < 128) {
        int pix = b * 256 + j0 + tid;
        float s = 0.f;
#pragma unroll
        for (int qs = 0; qs < 8; ++qs) s += dsum8[qs * 16384 + pix];
        float r = rsqrtf(s);
        dd[tid] = r;
        dscale[pix] = r;
    }
    __syncthreads();
    int jr = tid >> 7, m = tid & 127;
    for (int i = 0; i < 64; ++i) {
        int j = i * 2 + jr;
        long long qi = ((long long)(b * 256 + j0 + j)) * 128 + m;
        t[j][m] = f2b(dd[j] * b2f(q[qi]));
    }
    __syncthreads();
    for (int i = 0; i < 64; ++i) {
        int mm = i * 2 + jr;
        Pt[((long long)b << 15) + (mm << 8) + j0 + m] = t[m][mm];
    }
}

// One-shot weight/bias packing (see r10 layout)
__global__ void k_packall(const float* r0, const float* r1, const float* r2,
                          const float* convw, const float* c1w, const float* c3w,
                          const float* ckw, const float* gcnw,
                          const float* rb0, const float* rb1, const float* rb2,
                          const float* cb, const float* c1b, const float* ckbias,
                          ushort_t* wbig3, ushort_t* wfq, ushort_t* w3b,
                          ushort_t* gcnT, float* fqbias, float* fbias,
                          ushort_t* zpage) {
    int blk = blockIdx.x, tid = threadIdx.x;
    if (blk < 768) {
        __shared__ float lw[10240];
        int s = blk >> 8, o = blk & 255;
        const float* rate = s == 0 ? r0 : (s == 1 ? r1 : r2);
        for (int i = tid; i < 9216; i += 256) lw[i] = rate[(long long)o * 9216 + i];
        for (int i = tid; i < 1024; i += 256) lw[9216 + i] = convw[(long long)o * 1024 + i];
        __syncthreads();
        ushort_t* dst = wbig3 + (long long)blk * 10240;
        for (int i = tid; i < 10240; i += 256) {
            int tap = i >> 10, ci = i & 1023;
            float v = (tap < 9) ? lw[ci * 9 + tap] : lw[9216 + ci];
            dst[i] = f2b(v);
        }
        return;
    }
    const int R1 = 262144;            // wfq: conv1_w part
    const int R2 = R1 + 32768;        // wfq: ck_w part
    const int R3 = R2 + 786432;       // w3b
    const int R4 = R3 + 65536;        // gcnT
    const int R5 = R4 + 1152;         // fqbias
    const int R6 = R5 + 768;          // fbias
    const int R7 = R6 + 4096;         // zpage
    int base = (blk - 768) * 2048 + tid * 8;
#pragma unroll
    for (int k = 0; k < 8; ++k) {
        int i = base + k;
        if (i >= R7) return;
        if (i < R1) wfq[i] = f2b(c1w[i]);
        else if (i < R2) wfq[i] = f2b(ckw[i - R1]);
        else if (i < R3) w3b[i - R2] = f2b(c3w[i - R2]);
        else if (i < R4) {
            int ii = i - R3; int c2 = ii >> 8, c1 = ii & 255;
            gcnT[ii] = f2b(gcnw[c1 * 256 + c2]);
        } else if (i < R5) {
            int ii = i - R4;
            fqbias[ii] = (ii < 1024) ? c1b[ii] : ckbias[ii - 1024];
        } else if (i < R6) {
            int ii = i - R5; int s = ii >> 8, t = ii & 255;
            const float* rb = s == 0 ? rb0 : (s == 1 ? rb1 : rb2);
            fbias[ii] = rb[t] + cb[t];
        } else {
            zpage[i - R6] = 0;
        }
    }
}

__global__ void k_sentinel(float* o, int n, float v) {
    int i = blockIdx.x * 256 + threadIdx.x; if (i < n) o[i] = v;
}

// ---------------- launch ----------------
extern "C" void kernel_launch(void* const* d_in, const int* in_sizes, int n_in,
                              void* d_out, int out_size, void* d_ws, size_t ws_size,
                              hipStream_t stream) {
    const float* x_cur  = (const float*)d_in[0];
    const float* x_lat  = (const float*)d_in[1];
    const float* conv_w = (const float*)d_in[2];
    const float* conv_b = (const float*)d_in[3];
    const float* conv1_w = (const float*)d_in[4];
    const float* conv1_b = (const float*)d_in[5];
    const float* conv3_w = (const float*)d_in[6];
    const float* conv3_b = (const float*)d_in[7];
    const float* rate_w[3] = {(const float*)d_in[8], (const float*)d_in[10], (const float*)d_in[12]};
    const float* rate_b[3] = {(const float*)d_in[9], (const float*)d_in[11], (const float*)d_in[13]};
    const float* ck_w  = (const float*)d_in[14];
    const float* ck_b  = (const float*)d_in[15];
    const float* avg_w = (const float*)d_in[16];
    const float* max_w = (const float*)d_in[17];
    const float* gcn_w = (const float*)d_in[18];
    float* out = (float*)d_out;

    char* w = (char*)d_ws;
    auto take = [&](size_t bytes) { void* p = (void*)w; w += (bytes + 255) & ~(size_t)255; return p; };
    ushort_t* xsum   = (ushort_t*)take(16384ll * 1024 * 2);    // 33.55MB
    ushort_t* feat   = (ushort_t*)take(16384ll * 1024 * 2);    // 33.55MB
    ushort_t* fbufP[2];                                        // stage-parity
    fbufP[0] = (ushort_t*)take(16384ll * 256 * 2);             // 8.39MB
    fbufP[1] = (ushort_t*)take(16384ll * 256 * 2);             // 8.39MB
    ushort_t* qbufP[2];
    qbufP[0] = (ushort_t*)take(16384ll * 128 * 2);             // 4.19MB
    qbufP[1] = (ushort_t*)take(16384ll * 128 * 2);             // 4.19MB
    ushort_t* xgt    = (ushort_t*)take(64ll * 256 * 256 * 2);  // 8.39MB
    ushort_t* Pt     = (ushort_t*)take(64ll * 128 * 256 * 2);  // 4.19MB
    ushort_t* Htn    = (ushort_t*)take(64ll * 256 * 128 * 2);  // 4.19MB
    ushort_t* wbig3  = (ushort_t*)take(3ll * 256 * 10240 * 2); // 15.73MB
    ushort_t* wfq    = (ushort_t*)take(1152ll * 256 * 2);
    ushort_t* w3b    = (ushort_t*)take(1024ll * 768 * 2);
    ushort_t* gcnT   = (ushort_t*)take(256ll * 256 * 2);
    ushort_t* zpage  = (ushort_t*)take(8192);
    float*    fqbias = (float*)take(1152 * 4);
    float*    fbias  = (float*)take(3 * 256 * 4);
    float*    cwbP[2];
    cwbP[0] = (float*)take(64 * 128 * 4);
    cwbP[1] = (float*)take(64 * 128 * 4);
    float*    dscale = (float*)take(64 * 256 * 4);
    float*    dsum8  = (float*)take(8ll * 64 * 256 * 4);
    ushort_t* catb   = (ushort_t*)take(16384ll * 768 * 2);     // 25.17MB
    ushort_t* ftmp   = (ushort_t*)take(5ll * 16384 * 256 * 2); // 41.94MB
    size_t need = (size_t)(w - (char*)d_ws);                   // ~195MB (<=204 proven)

    if (need > ws_size) {
        float v = 1.0e6f + (float)(ws_size >> 20);
        k_sentinel<<<(out_size + 255) / 256, 256, 0, stream>>>(out, out_size, v);
        return;
    }

    // per-stage GemmP builders
    auto PBIG = [&](int s) {
        GemmP p{};
        p.A = (s == 0) ? xsum : feat;
        p.B = wbig3 + (long long)s * 256 * 10240; p.ldb = 10240;
        p.Ksub = 2048; p.kSplit = 2048; p.dil = 1 << s;
        p.obf = ftmp; p.oBatch = 16384ll * 256;
        p.zpage = zpage;
        return p;
    };
    auto PSIG = [&](int s) {
        GemmP p{};
        p.A = qbufP[s & 1]; p.aBatch = 32768; p.lda = 128;
        p.B = qbufP[s & 1]; p.bBatch = 32768; p.ldb = 128;
        p.Ksub = 128; p.dsum = dsum8; p.cw = cwbP[s & 1];
        return p;
    };
    auto PXG = [&](int s) {
        GemmP p{};
        p.A = gcnT; p.aBatch = 0;            p.lda = 256;
        p.B = fbufP[s & 1]; p.bBatch = 65536; p.ldb = 256;
        p.Ksub = 256;
        p.obf = xgt; p.oBatch = 65536; p.ldo = 256;
        return p;
    };
    auto PHTN = [&](int s) {
        GemmP p{};
        p.A = xgt; p.aBatch = 65536; p.lda = 256;
        p.B = Pt;  p.bBatch = 32768; p.ldb = 256;
        p.Ksub = 256; p.cw = cwbP[s & 1];
        p.obf = Htn; p.oBatch = 32768; p.ldo = 128;
        return p;
    };
    auto PY = [&](int s) {
        GemmP p{};
        p.A = fbufP[s & 1]; p.aBatch = 65536; p.lda = 256;
        p.B = gcnT; p.bBatch = 0;             p.ldb = 256;
        p.A2 = qbufP[s & 1]; p.a2Batch = 32768; p.lda2 = 128; p.rscale = dscale;
        p.B2 = Htn;          p.b2Batch = 32768; p.ldb2 = 128;
        p.Ksub = 384;
        p.res = fbufP[s & 1]; p.resBatch = 65536; p.ldres = 256;
        p.obf = catb + s * 256; p.oBatch = 256ll * 768; p.ldo = 768;
        return p;
    };
    auto PFQ = [&](int s) {
        GemmP p{};
        p.A = fbufP[s & 1]; p.lda = 256; p.B = wfq; p.ldb = 256;
        p.Ksub = 256; p.bias = fqbias;
        p.res = xsum;
        p.obf = feat; p.obf2 = qbufP[s & 1];
        return p;
    };
    GemmP pz{};  // dummy for unused roles

    k_packall<<<768 + 563, 256, 0, stream>>>(
        rate_w[0], rate_w[1], rate_w[2], conv_w, conv1_w, conv3_w, ck_w, gcn_w,
        rate_b[0], rate_b[1], rate_b[2], conv_b, conv1_b, ck_b,
        wbig3, wfq, w3b, gcnT, fqbias, fbias, zpage);
    k_upsum<<<dim3(64, 16), 256, 0, stream>>>(x_cur, x_lat, xsum);

    // ---- software-pipelined schedule: stage-s GR tail rides inside stage-
    // (s+1) dispatches (independent after FQ_s; parity buffers break WAR) ----
    // 1: BIG_0
    k_big_sig_y<<<dim3(128, 2, 5), 256, 0, stream>>>(PBIG(0), pz, pz, pz);
    // 2: combine_0
    k_combine<<<2048, 256, 0, stream>>>(ftmp, fbias + 0 * 256, fbufP[0]);
    // 3: FQ_0 + pool_0
    k_fqpool_htn<<<dim3(128, 10), 256, 0, stream>>>(PFQ(0), pz, avg_w, max_w, cwbP[0]);
    // 4: BIG_1 || sigxg_0
    k_big_sig_y<<<dim3(128, 2, 13), 256, 0, stream>>>(PBIG(1), PSIG(0), PXG(0), pz);
    // 5: combine_1
    k_combine<<<2048, 256, 0, stream>>>(ftmp, fbias + 1 * 256, fbufP[1]);
    // 6: pscale_0
    k_pscale<<<dim3(2, 64), 256, 0, stream>>>(qbufP[0], dsum8, dscale, Pt);
    // 7: FQ_1 + pool_1 || Htn_0
    k_fqpool_htn<<<dim3(128, 14), 256, 0, stream>>>(PFQ(1), PHTN(0), avg_w, max_w, cwbP[1]);
    // 8: BIG_2 || sigxg_1 || Y_0
    k_big_sig_y<<<dim3(128, 2, 17), 256, 0, stream>>>(PBIG(2), PSIG(1), PXG(1), PY(0));
    // 9: combine_2
    k_combine<<<2048, 256, 0, stream>>>(ftmp, fbias + 2 * 256, fbufP[0]);
    // 10: pscale_1
    k_pscale<<<dim3(2, 64), 256, 0, stream>>>(qbufP[1], dsum8, dscale, Pt);
    // 11: q_2 + pool_2 || Htn_1
    {
        GemmP pq{};
        pq.A = fbufP[0]; pq.lda = 256; pq.B = wfq + 1024 * 256; pq.ldb = 256;
        pq.Ksub = 256;
        pq.bias = ck_b; pq.obf = qbufP[0]; pq.ldo = 128;
        k_qpool_htn<<<dim3(256, 5), 256, 0, stream>>>(pq, PHTN(1), avg_w, max_w, cwbP[0]);
    }
    // 12: sigxg_2 || Y_1
    k_sigxg_y<<<dim3(4, 4, 192), 256, 0, stream>>>(PSIG(2), PXG(2), PY(1));
    // 13: pscale_2
    k_pscale<<<dim3(2, 64), 256, 0, stream>>>(qbufP[0], dsum8, dscale, Pt);
    // 14: Htn_2
    gemm_k<64, 64, 0, EPI_NEGCW><<<dim3(4, 2, 64), 256, 0, stream>>>(PHTN(2));
    // 15: Y_2
    gemm_k<64, 64, 2, EPI_Y><<<dim3(4, 4, 64), 256, 0, stream>>>(PY(2));
    // 16: OUT = cat @ w3^T + b (coalesced px writes)
    {
        GemmP p{};
        p.A = w3b;  p.lda = 768;
        p.B = catb; p.ldb = 768;
        p.Ksub = 768; p.bias = conv3_b; p.of32 = out;
        gemm_k<64, 128, 0, EPI_OUTT><<<dim3(16, 128, 1), 256, 0, stream>>>(p);
    }
}